// Round 1
// baseline (1611.735 us; speedup 1.0000x reference)
//
#include <hip/hip_runtime.h>
#include <hip/hip_bf16.h>
#include <math.h>

// Problem constants
constexpr int BQ = 8;      // batch
constexpr int CH = 8;      // channels
constexpr int TT = 2048;   // time frames
constexpr int FB = 257;    // freq bins
constexpr int HD = 256;    // hidden
constexpr int DHD = 64;    // head dim
constexpr int WN = 512;    // ffn dim
constexpr int HF = 128;    // H/2
constexpr int RR = BQ * TT;  // 16384 rows per channel slice

// ---------------------------------------------------------------------------
// Generic fp32 tiled GEMM: C[M,N] = act(A @ W[K,N] + bias[N])
// A rows are addressed in groups of 2048: row r -> A + (r>>11)*grpStride + (r&2047)*lda
// (handles both contiguous buffers and [B,C,T,*] channel slices).
// BM=128, BN=64, BK=16, 256 threads, 8x4 outputs/thread. M must be 16384.
// Gated: returns immediately if *gate < 0.5 (ACT ponder early-exit).
// ---------------------------------------------------------------------------
template<int ACT>
__global__ __launch_bounds__(256) void gemm_k(
    const float* __restrict__ A, const float* __restrict__ W,
    const float* __restrict__ bias, float* __restrict__ C,
    int N, int K, int lda, long grpStride, int ldc,
    const float* __restrict__ gate)
{
  if (gate && gate[0] < 0.5f) return;
  __shared__ float As[16][132];   // transposed: As[k][m]  (row 528B, 16B aligned)
  __shared__ float Bs[16][68];    // Bs[k][n]              (row 272B, 16B aligned)
  const int tid = threadIdx.x;
  const int row0 = blockIdx.x * 128;
  const int n0 = blockIdx.y * 64;
  const float* Ab = A + (long)(row0 >> 11) * grpStride + (long)(row0 & 2047) * lda;

  const int f4 = (tid & 3) * 4;     // vector-A path: k offset
  const int rA = tid >> 2;          // vector-A path: row
  const int kkS = tid & 15;         // scalar-A path: k
  const int rAS = tid >> 4;         // scalar-A path: row base
  const int cf = (tid & 15) * 4;    // B: col offset
  const int kB = tid >> 4;          // B: k row
  const int tr = (tid >> 4) * 8;    // output rows tr..tr+7
  const int tc = (tid & 15) * 4;    // output cols tc..tc+3

  const bool avec = ((lda & 3) == 0);
  const bool bvec = ((N & 3) == 0);
  const bool nfull = (n0 + 64 <= N);

  float acc[8][4];
  #pragma unroll
  for (int i = 0; i < 8; i++)
    #pragma unroll
    for (int j = 0; j < 4; j++) acc[i][j] = 0.f;

  for (int k0 = 0; k0 < K; k0 += 16) {
    const bool kfull = (k0 + 16 <= K);
    // ---- stage A tile ----
    if (avec && kfull) {
      #pragma unroll
      for (int i = 0; i < 2; i++) {
        const int rr = rA + i * 64;
        const float4 v = *(const float4*)(Ab + (long)rr * lda + k0 + f4);
        As[f4 + 0][rr] = v.x; As[f4 + 1][rr] = v.y;
        As[f4 + 2][rr] = v.z; As[f4 + 3][rr] = v.w;
      }
    } else {
      const int k = k0 + kkS;
      const bool kok = (k < K);
      #pragma unroll
      for (int i = 0; i < 8; i++) {
        const int rr = rAS + i * 16;
        As[kkS][rr] = kok ? Ab[(long)rr * lda + k] : 0.f;
      }
    }
    // ---- stage B tile ----
    {
      const int k = k0 + kB;
      if (bvec && kfull && nfull) {
        *(float4*)&Bs[kB][cf] = *(const float4*)(W + (long)k * N + n0 + cf);
      } else {
        #pragma unroll
        for (int j = 0; j < 4; j++) {
          const int c = n0 + cf + j;
          Bs[kB][cf + j] = (k < K && c < N) ? W[(long)k * N + c] : 0.f;
        }
      }
    }
    __syncthreads();
    // ---- MACs ----
    #pragma unroll
    for (int k = 0; k < 16; k++) {
      const float4 a0 = *(const float4*)&As[k][tr];
      const float4 a1 = *(const float4*)&As[k][tr + 4];
      const float4 b0 = *(const float4*)&Bs[k][tc];
      const float av[8] = {a0.x, a0.y, a0.z, a0.w, a1.x, a1.y, a1.z, a1.w};
      const float bw[4] = {b0.x, b0.y, b0.z, b0.w};
      #pragma unroll
      for (int i = 0; i < 8; i++)
        #pragma unroll
        for (int j = 0; j < 4; j++)
          acc[i][j] = fmaf(av[i], bw[j], acc[i][j]);
    }
    __syncthreads();
  }
  // ---- epilogue ----
  float bb[4];
  #pragma unroll
  for (int j = 0; j < 4; j++) {
    const int c = n0 + tc + j;
    bb[j] = (c < N) ? bias[c] : 0.f;
  }
  const bool cvec = ((ldc & 3) == 0) && (n0 + tc + 4 <= N);
  #pragma unroll
  for (int i = 0; i < 8; i++) {
    const long r = row0 + tr + i;
    if (cvec) {
      float4 v;
      v.x = acc[i][0] + bb[0]; v.y = acc[i][1] + bb[1];
      v.z = acc[i][2] + bb[2]; v.w = acc[i][3] + bb[3];
      if (ACT == 1) {
        v.x = fmaxf(v.x, 0.f); v.y = fmaxf(v.y, 0.f);
        v.z = fmaxf(v.z, 0.f); v.w = fmaxf(v.w, 0.f);
      }
      *(float4*)(C + r * ldc + n0 + tc) = v;
    } else {
      #pragma unroll
      for (int j = 0; j < 4; j++) {
        const int c = n0 + tc + j;
        if (c < N) {
          float v = acc[i][j] + bb[j];
          if (ACT == 1) v = fmaxf(v, 0.f);
          C[r * ldc + c] = v;
        }
      }
    }
  }
}

// ---------------------------------------------------------------------------
// Per-time-frame attention over channels. One wave per head; 4 rows per block.
// NCc = number of kv channels (compile-time so score arrays stay in registers).
// ---------------------------------------------------------------------------
template<int NCc>
__global__ __launch_bounds__(256) void attn_k(
    const float* __restrict__ Q, const float* __restrict__ Ks,
    const float* __restrict__ Vs, float* __restrict__ ctx,
    const float* __restrict__ gate)
{
  if (gate[0] < 0.5f) return;
  const int w = threadIdx.x >> 6;   // head
  const int l = threadIdx.x & 63;   // dh lane
  for (int rr = 0; rr < 4; rr++) {
    const long r = (long)blockIdx.x * 4 + rr;   // b*T + t
    const float qv = Q[r * HD + w * DHD + l];
    float sc[NCc];
    #pragma unroll
    for (int c = 0; c < NCc; c++) {
      float p = qv * Ks[((long)c * RR + r) * HD + w * DHD + l];
      #pragma unroll
      for (int s = 32; s > 0; s >>= 1) p += __shfl_xor(p, s, 64);
      sc[c] = p * 0.125f;   // 1/sqrt(64)
    }
    float m = sc[0];
    #pragma unroll
    for (int c = 1; c < NCc; c++) m = fmaxf(m, sc[c]);
    float a[NCc];
    float den = 0.f;
    #pragma unroll
    for (int c = 0; c < NCc; c++) { a[c] = expf(sc[c] - m); den += a[c]; }
    float cv = 0.f;
    #pragma unroll
    for (int c = 0; c < NCc; c++) {
      cv = fmaf(a[c] / den, Vs[((long)c * RR + r) * HD + w * DHD + l], cv);
    }
    ctx[r * HD + w * DHD + l] = cv;
  }
}

// ---------------------------------------------------------------------------
// h_out = LayerNorm(X + Y) * g + b   over H=256. 8 rows per block.
// ---------------------------------------------------------------------------
__global__ __launch_bounds__(256) void ln_res_k(
    const float* __restrict__ X, const float* __restrict__ Y,
    const float* __restrict__ g, const float* __restrict__ b,
    float* __restrict__ O, const float* __restrict__ gate)
{
  if (gate[0] < 0.5f) return;
  __shared__ float red[4];
  const int tid = threadIdx.x;
  for (int rr = 0; rr < 8; rr++) {
    const long r = (long)blockIdx.x * 8 + rr;
    const float v = X[r * HD + tid] + Y[r * HD + tid];
    float s = v;
    #pragma unroll
    for (int i = 32; i > 0; i >>= 1) s += __shfl_xor(s, i, 64);
    if ((tid & 63) == 0) red[tid >> 6] = s;
    __syncthreads();
    const float mean = (red[0] + red[1] + red[2] + red[3]) * (1.f / HD);
    __syncthreads();
    const float d = v - mean;
    float sq = d * d;
    #pragma unroll
    for (int i = 32; i > 0; i >>= 1) sq += __shfl_xor(sq, i, 64);
    if ((tid & 63) == 0) red[tid >> 6] = sq;
    __syncthreads();
    const float var = (red[0] + red[1] + red[2] + red[3]) * (1.f / HD);
    const float inv = 1.f / sqrtf(var + 1e-5f);
    O[r * HD + tid] = d * inv * g[tid] + b[tid];
    __syncthreads();
  }
}

// ---------------------------------------------------------------------------
// ACT ponder update. Computes cur = sigmoid((s1 . Ws2 + bs2 - ps_a)/(ps_b+1e-8))
// (or 1.0 on the last channel), then the exact reference update. 8 rows/block.
// Sets *anyFlag if any row is still active after the update.
// ---------------------------------------------------------------------------
__global__ __launch_bounds__(256) void act_k(
    const float* __restrict__ s1, const float* __restrict__ Ws2,
    const float* __restrict__ bs2, const float* __restrict__ psa,
    const float* __restrict__ psb, const float* __restrict__ hh,
    float* __restrict__ cum, float* __restrict__ rem,
    float* __restrict__ still, float* __restrict__ pc,
    float* __restrict__ out, int lastIter,
    const float* __restrict__ gate, int* __restrict__ anyFlag)
{
  if (gate[0] < 0.5f) return;
  __shared__ float red[4];
  const int tid = threadIdx.x;
  for (int rr = 0; rr < 8; rr++) {
    const long r = (long)blockIdx.x * 8 + rr;
    float curv;
    if (!lastIter) {
      float p = (tid < HF) ? s1[r * HF + tid] * Ws2[tid] : 0.f;
      #pragma unroll
      for (int i = 32; i > 0; i >>= 1) p += __shfl_xor(p, i, 64);
      if ((tid & 63) == 0) red[tid >> 6] = p;
      __syncthreads();
      const float s = red[0] + red[1] + red[2] + red[3] + bs2[0];
      const float z = (s - psa[0]) / (psb[0] + 1e-8f);
      curv = 1.f / (1.f + expf(-z));
      __syncthreads();
    } else {
      curv = 1.f;
    }
    const float cu = cum[r], re = rem[r], st = still[r], pp = pc[r];
    const float cum_n = cu + curv * st;
    float pc_n = pp + st;
    const float still_n = (cum_n < 0.9999f) ? 1.f : 0.f;
    const float w = curv * still_n + re * (1.f - still_n);
    out[r * HD + tid] += hh[r * HD + tid] * w;
    const float rem_n = re - curv * still_n;
    pc_n += rem_n * (1.f - still_n);
    if (tid == 0) {
      cum[r] = cum_n; rem[r] = rem_n; still[r] = still_n; pc[r] = pc_n;
      if (still_n > 0.5f) *anyFlag = 1;
    }
    __syncthreads();
  }
}

__global__ void gate_k(const float* gprev, float* gnext, const int* anyFlag) {
  gnext[0] = (gprev[0] > 0.5f && *anyFlag != 0) ? 1.f : 0.f;
}

__global__ __launch_bounds__(256) void init_k(
    float* out, float* cum, float* rem, float* still, float* pc,
    float* gate, int* flags)
{
  const long gid = (long)blockIdx.x * 256 + threadIdx.x;
  const long n = (long)RR * HD;
  for (long i = gid; i < n; i += (long)gridDim.x * 256) out[i] = 0.f;
  if (gid < RR) { cum[gid] = 0.f; rem[gid] = 1.f; still[gid] = 1.f; pc[gid] = 0.f; }
  if (gid == 0) {
    gate[0] = 1.f;
    for (int i = 1; i < 16; i++) gate[i] = 0.f;
    for (int i = 0; i < 8; i++) flags[i] = 0;
  }
}

__global__ __launch_bounds__(256) void pc_copy_k(const float* pc, float* o) {
  const int i = blockIdx.x * 256 + threadIdx.x;
  o[i] = pc[i];
}

// ---------------------------------------------------------------------------
extern "C" void kernel_launch(void* const* d_in, const int* in_sizes, int n_in,
                              void* d_out, int out_size, void* d_ws, size_t ws_size,
                              hipStream_t stream) {
  const float* x    = (const float*)d_in[0];
  const float* W_in = (const float*)d_in[1];
  const float* b_in = (const float*)d_in[2];
  const float* W_out= (const float*)d_in[3];
  const float* b_out= (const float*)d_in[4];
  const float* Wq   = (const float*)d_in[5];
  const float* bq   = (const float*)d_in[6];
  const float* Wk   = (const float*)d_in[7];
  const float* bk   = (const float*)d_in[8];
  const float* Wv   = (const float*)d_in[9];
  const float* bv   = (const float*)d_in[10];
  const float* Wo   = (const float*)d_in[11];
  const float* bo   = (const float*)d_in[12];
  const float* ln1g = (const float*)d_in[13];
  const float* ln1b = (const float*)d_in[14];
  const float* Wf1  = (const float*)d_in[15];
  const float* bf1  = (const float*)d_in[16];
  const float* Wf2  = (const float*)d_in[17];
  const float* bf2  = (const float*)d_in[18];
  const float* ln2g = (const float*)d_in[19];
  const float* ln2b = (const float*)d_in[20];
  const float* Ws1  = (const float*)d_in[21];
  const float* bs1  = (const float*)d_in[22];
  const float* Ws2  = (const float*)d_in[23];
  const float* bs2  = (const float*)d_in[24];
  const float* psa  = (const float*)d_in[25];
  const float* psb  = (const float*)d_in[26];

  float* ws = (float*)d_ws;
  long off = 0;
  float* lin1 = ws + off; off += (long)CH * RR * HD;   // [C][B*T][H]
  float* Ks   = ws + off; off += (long)CH * RR * HD;
  float* Vs   = ws + off; off += (long)CH * RR * HD;
  float* t1   = ws + off; off += (long)RR * WN;        // ffn hidden; aliases Qb
  float* ctx  = ws + off; off += (long)RR * HD;        // aliases s1
  float* gb   = ws + off; off += (long)RR * HD;        // gemm epilogue scratch
  float* h1   = ws + off; off += (long)RR * HD;
  float* hh   = ws + off; off += (long)RR * HD;
  float* outb = ws + off; off += (long)RR * HD;
  float* cum  = ws + off; off += RR;
  float* rem  = ws + off; off += RR;
  float* still= ws + off; off += RR;
  float* pc   = ws + off; off += RR;
  float* gate = ws + off; off += 16;
  int*  flags = (int*)(ws + off); off += 8;
  float* Qb = t1;    // alias: Q consumed (attn) before t1 written (ffn)
  float* s1 = ctx;   // alias: ctx consumed (Wo gemm) before s1 written

  init_k<<<2048, 256, 0, stream>>>(outb, cum, rem, still, pc, gate, flags);

  const long grpH = 2048L * HD;   // contiguous group stride, lda=256
  for (int ci = 0; ci < CH; ci++) {
    const float* g = gate + ci;
    const float* Ac = lin1 + (long)ci * RR * HD;
    // lin1[:,ci] = relu(x[:,ci] @ W_in + b_in)   (x slice: group stride C*T*F)
    gemm_k<1><<<dim3(128, 4), 256, 0, stream>>>(
        x + (long)ci * TT * FB, W_in, b_in, lin1 + (long)ci * RR * HD,
        HD, FB, FB, (long)CH * TT * FB, HD, g);
    // Q / K / V projections for this channel only (done once, reused later)
    gemm_k<0><<<dim3(128, 4), 256, 0, stream>>>(Ac, Wq, bq, Qb, HD, HD, HD, grpH, HD, g);
    gemm_k<0><<<dim3(128, 4), 256, 0, stream>>>(Ac, Wk, bk, Ks + (long)ci * RR * HD, HD, HD, HD, grpH, HD, g);
    gemm_k<0><<<dim3(128, 4), 256, 0, stream>>>(Ac, Wv, bv, Vs + (long)ci * RR * HD, HD, HD, HD, grpH, HD, g);
    // attention over channels 0..ci
    switch (ci) {
      case 0: attn_k<1><<<4096, 256, 0, stream>>>(Qb, Ks, Vs, ctx, g); break;
      case 1: attn_k<2><<<4096, 256, 0, stream>>>(Qb, Ks, Vs, ctx, g); break;
      case 2: attn_k<3><<<4096, 256, 0, stream>>>(Qb, Ks, Vs, ctx, g); break;
      case 3: attn_k<4><<<4096, 256, 0, stream>>>(Qb, Ks, Vs, ctx, g); break;
      case 4: attn_k<5><<<4096, 256, 0, stream>>>(Qb, Ks, Vs, ctx, g); break;
      case 5: attn_k<6><<<4096, 256, 0, stream>>>(Qb, Ks, Vs, ctx, g); break;
      case 6: attn_k<7><<<4096, 256, 0, stream>>>(Qb, Ks, Vs, ctx, g); break;
      default: attn_k<8><<<4096, 256, 0, stream>>>(Qb, Ks, Vs, ctx, g); break;
    }
    // h1 = LN(q + ctx @ Wo + bo)
    gemm_k<0><<<dim3(128, 4), 256, 0, stream>>>(ctx, Wo, bo, gb, HD, HD, HD, grpH, HD, g);
    ln_res_k<<<2048, 256, 0, stream>>>(Ac, gb, ln1g, ln1b, h1, g);
    // hh = LN(h1 + relu(h1@Wf1+bf1)@Wf2+bf2)
    gemm_k<1><<<dim3(128, 8), 256, 0, stream>>>(h1, Wf1, bf1, t1, WN, HD, HD, grpH, WN, g);
    gemm_k<0><<<dim3(128, 4), 256, 0, stream>>>(t1, Wf2, bf2, gb, HD, WN, WN, 2048L * WN, HD, g);
    ln_res_k<<<2048, 256, 0, stream>>>(h1, gb, ln2g, ln2b, hh, g);
    // ponder probability + ACT state update
    if (ci < CH - 1)
      gemm_k<1><<<dim3(128, 2), 256, 0, stream>>>(hh, Ws1, bs1, s1, HF, HD, HD, grpH, HF, g);
    act_k<<<2048, 256, 0, stream>>>(s1, Ws2, bs2, psa, psb, hh, cum, rem, still, pc,
                                    outb, (ci == CH - 1) ? 1 : 0, g, flags + ci);
    gate_k<<<1, 1, 0, stream>>>(gate + ci, gate + ci + 1, flags + ci);
  }
  // encoder_out = relu(out @ W_out + b_out) -> d_out[0 : 16384*257]
  gemm_k<1><<<dim3(128, 5), 256, 0, stream>>>(
      outb, W_out, b_out, (float*)d_out, FB, HD, HD, grpH, FB, nullptr);
  // pc -> d_out tail
  pc_copy_k<<<64, 256, 0, stream>>>(pc, (float*)d_out + (long)RR * FB);
}

// Round 3
// 993.126 us; speedup vs baseline: 1.6229x; 1.6229x over previous
//
#include <hip/hip_runtime.h>
#include <hip/hip_bf16.h>
#include <math.h>

typedef _Float16 f16;
typedef _Float16 f16x8 __attribute__((ext_vector_type(8)));
typedef float f32x16 __attribute__((ext_vector_type(16)));

constexpr int CH = 8;      // channels
constexpr int TT = 2048;   // time frames
constexpr int FB = 257;    // freq bins
constexpr int HD = 256;    // hidden
constexpr int DHD = 64;    // head dim
constexpr int WN = 512;    // ffn dim
constexpr int HF = 128;    // H/2
constexpr int RR = 8 * TT; // 16384 rows
constexpr int KXP = 288;   // padded K for x / W_in (257 -> 288 = 9*32)

// ---------------------------------------------------------------------------
// Split-f16 MFMA GEMM:  C = act(A @ W + bias),  A,W pre-split into f16 hi/lo.
// A: [16384][K] (hi,lo), W: transposed-split [Npad][K] (hi,lo).
// Block 128x128, BK=32, 256 threads = 4 waves (2x2), wave tile 64x64 of
// 32x32x16 MFMA frags. 3 MFMAs per frag pair: Ah*Wh + Ah*Wl + Al*Wh
// (error ~2^-22 rel, fp32-class). Gated early-exit for dead ACT iterations.
// ---------------------------------------------------------------------------
template<int ACT, int WF32, int WF16, int QKV>
__global__ __launch_bounds__(256) void gemm_f16s(
    const f16* __restrict__ Ahi, const f16* __restrict__ Alo, int K,
    const f16* __restrict__ Bhi, const f16* __restrict__ Blo,
    const float* __restrict__ bias, const float* __restrict__ bias1,
    const float* __restrict__ bias2,
    float* __restrict__ C0, float* __restrict__ C1, float* __restrict__ C2,
    int ldc, f16* __restrict__ Chi, f16* __restrict__ Clo, int ldf,
    int Nreal, const float* __restrict__ gate)
{
  if (gate && gate[0] < 0.5f) return;
  __shared__ f16 As[2][128][40];   // [hi/lo][row][k] (+8 f16 pad: 2-way banks)
  __shared__ f16 Bs[2][128][40];
  const int tid = threadIdx.x;
  const int m0 = blockIdx.x * 128;
  const int n0 = blockIdx.y * 128;
  const int q = tid & 3, r = tid >> 2;          // staging: 4 lanes/row
  const int lane = tid & 63, wave = tid >> 6;
  const int wm = wave & 1, wn = wave >> 1;      // 2x2 wave grid
  const int lr = lane & 31, lg = lane >> 5;     // frag row/col, k-group

  f32x16 acc[2][2];
  #pragma unroll
  for (int mf = 0; mf < 2; mf++)
    #pragma unroll
    for (int nf = 0; nf < 2; nf++)
      #pragma unroll
      for (int g = 0; g < 16; g++) acc[mf][nf][g] = 0.f;

  f16x8 sAh0, sAh1, sAl0, sAl1, sBh0, sBh1, sBl0, sBl1;
  const long aoff = (long)(m0 + r) * K + q * 8;
  const long boff = (long)(n0 + r) * K + q * 8;
  const long hstep = (long)64 * K;

  // preload tile 0
  {
    sAh0 = *(const f16x8*)(Ahi + aoff);  sAh1 = *(const f16x8*)(Ahi + aoff + hstep);
    sAl0 = *(const f16x8*)(Alo + aoff);  sAl1 = *(const f16x8*)(Alo + aoff + hstep);
    sBh0 = *(const f16x8*)(Bhi + boff);  sBh1 = *(const f16x8*)(Bhi + boff + hstep);
    sBl0 = *(const f16x8*)(Blo + boff);  sBl1 = *(const f16x8*)(Blo + boff + hstep);
  }

  for (int k0 = 0; k0 < K; k0 += 32) {
    __syncthreads();   // previous MAC readers done before overwrite
    *(f16x8*)&As[0][r][q * 8] = sAh0;  *(f16x8*)&As[0][r + 64][q * 8] = sAh1;
    *(f16x8*)&As[1][r][q * 8] = sAl0;  *(f16x8*)&As[1][r + 64][q * 8] = sAl1;
    *(f16x8*)&Bs[0][r][q * 8] = sBh0;  *(f16x8*)&Bs[0][r + 64][q * 8] = sBh1;
    *(f16x8*)&Bs[1][r][q * 8] = sBl0;  *(f16x8*)&Bs[1][r + 64][q * 8] = sBl1;
    __syncthreads();
    if (k0 + 32 < K) {   // prefetch next tile; latency hides under MFMAs
      const long a2 = aoff + k0 + 32, b2 = boff + k0 + 32;
      sAh0 = *(const f16x8*)(Ahi + a2);  sAh1 = *(const f16x8*)(Ahi + a2 + hstep);
      sAl0 = *(const f16x8*)(Alo + a2);  sAl1 = *(const f16x8*)(Alo + a2 + hstep);
      sBh0 = *(const f16x8*)(Bhi + b2);  sBh1 = *(const f16x8*)(Bhi + b2 + hstep);
      sBl0 = *(const f16x8*)(Blo + b2);  sBl1 = *(const f16x8*)(Blo + b2 + hstep);
    }
    #pragma unroll
    for (int kh = 0; kh < 2; kh++) {
      const int kk = kh * 16 + lg * 8;
      f16x8 ah[2], al[2], bh[2], bl[2];
      #pragma unroll
      for (int mf = 0; mf < 2; mf++) {
        const int mm = wm * 64 + mf * 32 + lr;
        ah[mf] = *(const f16x8*)&As[0][mm][kk];
        al[mf] = *(const f16x8*)&As[1][mm][kk];
      }
      #pragma unroll
      for (int nf = 0; nf < 2; nf++) {
        const int nn = wn * 64 + nf * 32 + lr;
        bh[nf] = *(const f16x8*)&Bs[0][nn][kk];
        bl[nf] = *(const f16x8*)&Bs[1][nn][kk];
      }
      #pragma unroll
      for (int mf = 0; mf < 2; mf++)
        #pragma unroll
        for (int nf = 0; nf < 2; nf++) {
          acc[mf][nf] = __builtin_amdgcn_mfma_f32_32x32x16_f16(al[mf], bh[nf], acc[mf][nf], 0, 0, 0);
          acc[mf][nf] = __builtin_amdgcn_mfma_f32_32x32x16_f16(ah[mf], bl[nf], acc[mf][nf], 0, 0, 0);
          acc[mf][nf] = __builtin_amdgcn_mfma_f32_32x32x16_f16(ah[mf], bh[nf], acc[mf][nf], 0, 0, 0);
        }
    }
  }

  // epilogue: C/D layout col=lane&31, row=(g&3)+8*(g>>2)+4*(lane>>5)
  #pragma unroll
  for (int mf = 0; mf < 2; mf++)
    #pragma unroll
    for (int nf = 0; nf < 2; nf++) {
      const int col = n0 + wn * 64 + nf * 32 + lr;
      const float* bp = bias;
      float* Cp = C0;
      int cc = col;
      if (QKV) {
        const int sel = col >> 8;
        cc = col & 255;
        Cp = sel == 0 ? C0 : (sel == 1 ? C1 : C2);
        bp = sel == 0 ? bias : (sel == 1 ? bias1 : bias2);
      }
      const float bb = (col < Nreal) ? bp[cc] : 0.f;
      #pragma unroll
      for (int g = 0; g < 16; g++) {
        const long row = m0 + wm * 64 + mf * 32 + (g & 3) + 8 * (g >> 2) + 4 * lg;
        float v = acc[mf][nf][g] + bb;
        if (ACT) v = fmaxf(v, 0.f);
        if (col < Nreal) {
          if (WF32) Cp[row * (long)ldc + cc] = v;
          if (WF16) {
            const f16 hi = (f16)v;
            Chi[row * (long)ldf + col] = hi;
            Clo[row * (long)ldf + col] = (f16)(v - (float)hi);
          }
        }
      }
    }
}

// ---------------------------------------------------------------------------
// Weight transpose + f16 hi/lo split (one-time). blockIdx.y selects target.
// ---------------------------------------------------------------------------
__global__ __launch_bounds__(256) void wsplit_k(
    const float* __restrict__ W_in, const float* __restrict__ Wq,
    const float* __restrict__ Wk, const float* __restrict__ Wv,
    const float* __restrict__ Wo, const float* __restrict__ Wf1,
    const float* __restrict__ Wf2, const float* __restrict__ Ws1,
    const float* __restrict__ Wout,
    f16* __restrict__ WinThi, f16* __restrict__ WinTlo,
    f16* __restrict__ Wqkvhi, f16* __restrict__ Wqkvlo,
    f16* __restrict__ WoThi,  f16* __restrict__ WoTlo,
    f16* __restrict__ Wf1Thi, f16* __restrict__ Wf1Tlo,
    f16* __restrict__ Wf2Thi, f16* __restrict__ Wf2Tlo,
    f16* __restrict__ Ws1Thi, f16* __restrict__ Ws1Tlo,
    f16* __restrict__ WoutThi, f16* __restrict__ WoutTlo)
{
  const int y = blockIdx.y;
  const long idx = (long)blockIdx.x * 256 + threadIdx.x;
  int Npad, Kpad, Ksrc;
  f16 *dh, *dl;
  switch (y) {
    case 0: Npad = 256; Kpad = 288; Ksrc = 257; dh = WinThi;  dl = WinTlo;  break;
    case 1: Npad = 768; Kpad = 256; Ksrc = 256; dh = Wqkvhi;  dl = Wqkvlo;  break;
    case 2: Npad = 256; Kpad = 256; Ksrc = 256; dh = WoThi;   dl = WoTlo;   break;
    case 3: Npad = 512; Kpad = 256; Ksrc = 256; dh = Wf1Thi;  dl = Wf1Tlo;  break;
    case 4: Npad = 256; Kpad = 512; Ksrc = 512; dh = Wf2Thi;  dl = Wf2Tlo;  break;
    case 5: Npad = 128; Kpad = 256; Ksrc = 256; dh = Ws1Thi;  dl = Ws1Tlo;  break;
    default: Npad = 384; Kpad = 256; Ksrc = 256; dh = WoutThi; dl = WoutTlo; break;
  }
  if (idx >= (long)Npad * Kpad) return;
  const int n = (int)(idx / Kpad), k = (int)(idx % Kpad);
  float v = 0.f;
  if (k < Ksrc) {
    switch (y) {
      case 0: v = W_in[(long)k * 256 + n]; break;
      case 1: { const int sel = n >> 8;
                const float* s = sel == 0 ? Wq : (sel == 1 ? Wk : Wv);
                v = s[(long)k * 256 + (n & 255)]; } break;
      case 2: v = Wo[(long)k * 256 + n]; break;
      case 3: v = Wf1[(long)k * 512 + n]; break;
      case 4: v = Wf2[(long)k * 256 + n]; break;
      case 5: v = Ws1[(long)k * 128 + n]; break;
      default: v = (n < 257) ? Wout[(long)k * 257 + n] : 0.f; break;
    }
  }
  const f16 hi = (f16)v;
  dh[idx] = hi;
  dl[idx] = (f16)(v - (float)hi);
}

// ---------------------------------------------------------------------------
// x[:,ci] slice -> padded f16 hi/lo [16384][288]. Gated.
// ---------------------------------------------------------------------------
__global__ __launch_bounds__(256) void xsplit_k(
    const float* __restrict__ x, int ci, f16* __restrict__ xh,
    f16* __restrict__ xl, const float* __restrict__ gate)
{
  if (gate[0] < 0.5f) return;
  const int sub = threadIdx.x >> 6, l = threadIdx.x & 63;
  const long rI = (long)blockIdx.x * 4 + sub;
  const int b = (int)(rI >> 11), t = (int)(rI & 2047);
  const float* src = x + ((long)(b * CH + ci) * TT + t) * FB;
  f16* dh = xh + rI * KXP;
  f16* dl = xl + rI * KXP;
  for (int f = l; f < KXP; f += 64) {
    const float v = (f < FB) ? src[f] : 0.f;
    const f16 hi = (f16)v;
    dh[f] = hi;
    dl[f] = (f16)(v - (float)hi);
  }
}

// ---------------------------------------------------------------------------
// Per-time-frame attention over channels; writes ctx as f16 hi/lo.
// ---------------------------------------------------------------------------
template<int NCc>
__global__ __launch_bounds__(256) void attn_k(
    const float* __restrict__ Q, const float* __restrict__ Ksp,
    const float* __restrict__ Vsp, f16* __restrict__ chi,
    f16* __restrict__ clo, const float* __restrict__ gate)
{
  if (gate[0] < 0.5f) return;
  const int w = threadIdx.x >> 6;   // head
  const int l = threadIdx.x & 63;   // dh lane
  for (int rr = 0; rr < 4; rr++) {
    const long r = (long)blockIdx.x * 4 + rr;
    const float qv = Q[r * HD + w * DHD + l];
    float sc[NCc];
    #pragma unroll
    for (int c = 0; c < NCc; c++) {
      float p = qv * Ksp[((long)c * RR + r) * HD + w * DHD + l];
      #pragma unroll
      for (int s = 32; s > 0; s >>= 1) p += __shfl_xor(p, s, 64);
      sc[c] = p * 0.125f;   // 1/sqrt(64)
    }
    float m = sc[0];
    #pragma unroll
    for (int c = 1; c < NCc; c++) m = fmaxf(m, sc[c]);
    float a[NCc];
    float den = 0.f;
    #pragma unroll
    for (int c = 0; c < NCc; c++) { a[c] = expf(sc[c] - m); den += a[c]; }
    float cv = 0.f;
    #pragma unroll
    for (int c = 0; c < NCc; c++)
      cv = fmaf(a[c] / den, Vsp[((long)c * RR + r) * HD + w * DHD + l], cv);
    const f16 hi = (f16)cv;
    chi[r * HD + w * DHD + l] = hi;
    clo[r * HD + w * DHD + l] = (f16)(cv - (float)hi);
  }
}

// ---------------------------------------------------------------------------
// O = LayerNorm(X + Y) * g + b over H=256; optional f16 hi/lo output.
// ---------------------------------------------------------------------------
template<int WF16>
__global__ __launch_bounds__(256) void ln_res_k(
    const float* __restrict__ X, const float* __restrict__ Y,
    const float* __restrict__ g, const float* __restrict__ b,
    float* __restrict__ O, f16* __restrict__ Ohi, f16* __restrict__ Olo,
    const float* __restrict__ gate)
{
  if (gate[0] < 0.5f) return;
  __shared__ float red[4];
  const int tid = threadIdx.x;
  for (int rr = 0; rr < 8; rr++) {
    const long r = (long)blockIdx.x * 8 + rr;
    const float v = X[r * HD + tid] + Y[r * HD + tid];
    float s = v;
    #pragma unroll
    for (int i = 32; i > 0; i >>= 1) s += __shfl_xor(s, i, 64);
    if ((tid & 63) == 0) red[tid >> 6] = s;
    __syncthreads();
    const float mean = (red[0] + red[1] + red[2] + red[3]) * (1.f / HD);
    __syncthreads();
    const float d = v - mean;
    float sq = d * d;
    #pragma unroll
    for (int i = 32; i > 0; i >>= 1) sq += __shfl_xor(sq, i, 64);
    if ((tid & 63) == 0) red[tid >> 6] = sq;
    __syncthreads();
    const float var = (red[0] + red[1] + red[2] + red[3]) * (1.f / HD);
    const float inv = 1.f / sqrtf(var + 1e-5f);
    const float o = d * inv * g[tid] + b[tid];
    O[r * HD + tid] = o;
    if (WF16) {
      const f16 hi = (f16)o;
      Ohi[r * HD + tid] = hi;
      Olo[r * HD + tid] = (f16)(o - (float)hi);
    }
    __syncthreads();
  }
}

// ---------------------------------------------------------------------------
// ACT ponder update (exact reference formulas). Writes out fp32 + f16 hi/lo.
// ---------------------------------------------------------------------------
__global__ __launch_bounds__(256) void act_k(
    const float* __restrict__ s1, const float* __restrict__ Ws2,
    const float* __restrict__ bs2, const float* __restrict__ psa,
    const float* __restrict__ psb, const float* __restrict__ hh,
    float* __restrict__ cum, float* __restrict__ rem,
    float* __restrict__ still, float* __restrict__ pc,
    float* __restrict__ out, f16* __restrict__ outhi, f16* __restrict__ outlo,
    int lastIter, const float* __restrict__ gate, int* __restrict__ anyFlag)
{
  if (gate[0] < 0.5f) return;
  __shared__ float red[4];
  const int tid = threadIdx.x;
  for (int rr = 0; rr < 8; rr++) {
    const long r = (long)blockIdx.x * 8 + rr;
    float curv;
    if (!lastIter) {
      float p = (tid < HF) ? s1[r * HF + tid] * Ws2[tid] : 0.f;
      #pragma unroll
      for (int i = 32; i > 0; i >>= 1) p += __shfl_xor(p, i, 64);
      if ((tid & 63) == 0) red[tid >> 6] = p;
      __syncthreads();
      const float s = red[0] + red[1] + red[2] + red[3] + bs2[0];
      const float z = (s - psa[0]) / (psb[0] + 1e-8f);
      curv = 1.f / (1.f + expf(-z));
      __syncthreads();
    } else {
      curv = 1.f;
    }
    const float cu = cum[r], re = rem[r], st = still[r], pp = pc[r];
    const float cum_n = cu + curv * st;
    float pc_n = pp + st;
    const float still_n = (cum_n < 0.9999f) ? 1.f : 0.f;
    const float w = curv * still_n + re * (1.f - still_n);
    const float newv = out[r * HD + tid] + hh[r * HD + tid] * w;
    out[r * HD + tid] = newv;
    const f16 hi = (f16)newv;
    outhi[r * HD + tid] = hi;
    outlo[r * HD + tid] = (f16)(newv - (float)hi);
    const float rem_n = re - curv * still_n;
    pc_n += rem_n * (1.f - still_n);
    if (tid == 0) {
      cum[r] = cum_n; rem[r] = rem_n; still[r] = still_n; pc[r] = pc_n;
      if (still_n > 0.5f) *anyFlag = 1;
    }
    __syncthreads();
  }
}

__global__ void gate_k(const float* gprev, float* gnext, const int* anyFlag) {
  gnext[0] = (gprev[0] > 0.5f && *anyFlag != 0) ? 1.f : 0.f;
}

__global__ __launch_bounds__(256) void init_k(
    float* out, float* cum, float* rem, float* still, float* pc,
    float* gate, int* flags)
{
  const long gid = (long)blockIdx.x * 256 + threadIdx.x;
  const long n = (long)RR * HD;
  for (long i = gid; i < n; i += (long)gridDim.x * 256) out[i] = 0.f;
  if (gid < RR) { cum[gid] = 0.f; rem[gid] = 1.f; still[gid] = 1.f; pc[gid] = 0.f; }
  if (gid == 0) {
    gate[0] = 1.f;
    for (int i = 1; i < 16; i++) gate[i] = 0.f;
    for (int i = 0; i < 8; i++) flags[i] = 0;
  }
}

__global__ __launch_bounds__(256) void pc_copy_k(const float* pc, float* o) {
  const int i = blockIdx.x * 256 + threadIdx.x;
  o[i] = pc[i];
}

// ---------------------------------------------------------------------------
extern "C" void kernel_launch(void* const* d_in, const int* in_sizes, int n_in,
                              void* d_out, int out_size, void* d_ws, size_t ws_size,
                              hipStream_t stream) {
  const float* x    = (const float*)d_in[0];
  const float* W_in = (const float*)d_in[1];
  const float* b_in = (const float*)d_in[2];
  const float* W_out= (const float*)d_in[3];
  const float* b_out= (const float*)d_in[4];
  const float* Wq   = (const float*)d_in[5];
  const float* bq   = (const float*)d_in[6];
  const float* Wk   = (const float*)d_in[7];
  const float* bk   = (const float*)d_in[8];
  const float* Wv   = (const float*)d_in[9];
  const float* bv   = (const float*)d_in[10];
  const float* Wo   = (const float*)d_in[11];
  const float* bo   = (const float*)d_in[12];
  const float* ln1g = (const float*)d_in[13];
  const float* ln1b = (const float*)d_in[14];
  const float* Wf1  = (const float*)d_in[15];
  const float* bf1  = (const float*)d_in[16];
  const float* Wf2  = (const float*)d_in[17];
  const float* bf2  = (const float*)d_in[18];
  const float* ln2g = (const float*)d_in[19];
  const float* ln2b = (const float*)d_in[20];
  const float* Ws1  = (const float*)d_in[21];
  const float* bs1  = (const float*)d_in[22];
  const float* Ws2  = (const float*)d_in[23];
  const float* bs2  = (const float*)d_in[24];
  const float* psa  = (const float*)d_in[25];
  const float* psb  = (const float*)d_in[26];

  float* ws = (float*)d_ws;
  long off = 0;
  auto alloc = [&](long n) { float* p = ws + off; off += n; return p; };
  float* Ks   = alloc((long)CH * RR * HD);
  float* Vs   = alloc((long)CH * RR * HD);
  float* lin1 = alloc((long)RR * HD);
  float* Qb   = alloc((long)RR * HD);
  float* gb   = alloc((long)RR * HD);
  float* h1   = alloc((long)RR * HD);
  float* hh   = alloc((long)RR * HD);
  float* outb = alloc((long)RR * HD);
  float* s1   = alloc((long)RR * HF);
  f16* xhi    = (f16*)alloc((long)RR * KXP / 2);
  f16* xlo    = (f16*)alloc((long)RR * KXP / 2);
  f16* lin1hi = (f16*)alloc((long)RR * HD / 2);
  f16* lin1lo = (f16*)alloc((long)RR * HD / 2);
  f16* ctxhi  = (f16*)alloc((long)RR * HD / 2);
  f16* ctxlo  = (f16*)alloc((long)RR * HD / 2);
  f16* h1hi   = (f16*)alloc((long)RR * HD / 2);
  f16* h1lo   = (f16*)alloc((long)RR * HD / 2);
  f16* hhhi   = (f16*)alloc((long)RR * HD / 2);
  f16* hhlo   = (f16*)alloc((long)RR * HD / 2);
  f16* t1hi   = (f16*)alloc((long)RR * WN / 2);
  f16* t1lo   = (f16*)alloc((long)RR * WN / 2);
  f16* outhi  = (f16*)alloc((long)RR * HD / 2);
  f16* outlo  = (f16*)alloc((long)RR * HD / 2);
  f16* WinThi = (f16*)alloc(256 * 288 / 2);
  f16* WinTlo = (f16*)alloc(256 * 288 / 2);
  f16* Wqkvhi = (f16*)alloc(768 * 256 / 2);
  f16* Wqkvlo = (f16*)alloc(768 * 256 / 2);
  f16* WoThi  = (f16*)alloc(256 * 256 / 2);
  f16* WoTlo  = (f16*)alloc(256 * 256 / 2);
  f16* Wf1Thi = (f16*)alloc(512 * 256 / 2);
  f16* Wf1Tlo = (f16*)alloc(512 * 256 / 2);
  f16* Wf2Thi = (f16*)alloc(256 * 512 / 2);
  f16* Wf2Tlo = (f16*)alloc(256 * 512 / 2);
  f16* Ws1Thi = (f16*)alloc(128 * 256 / 2);
  f16* Ws1Tlo = (f16*)alloc(128 * 256 / 2);
  f16* WoutThi= (f16*)alloc(384 * 256 / 2);
  f16* WoutTlo= (f16*)alloc(384 * 256 / 2);
  float* cum  = alloc(RR);
  float* rem  = alloc(RR);
  float* still= alloc(RR);
  float* pc   = alloc(RR);
  float* gate = alloc(16);
  int* flags  = (int*)alloc(8);

  init_k<<<2048, 256, 0, stream>>>(outb, cum, rem, still, pc, gate, flags);
  wsplit_k<<<dim3(768, 7), 256, 0, stream>>>(
      W_in, Wq, Wk, Wv, Wo, Wf1, Wf2, Ws1, W_out,
      WinThi, WinTlo, Wqkvhi, Wqkvlo, WoThi, WoTlo, Wf1Thi, Wf1Tlo,
      Wf2Thi, Wf2Tlo, Ws1Thi, Ws1Tlo, WoutThi, WoutTlo);

  for (int ci = 0; ci < CH; ci++) {
    const float* g = gate + ci;
    // x[:,ci] -> padded split
    xsplit_k<<<4096, 256, 0, stream>>>(x, ci, xhi, xlo, g);
    // lin1 = relu(x @ W_in + b_in)  (fp32 + hi/lo)
    gemm_f16s<1, 1, 1, 0><<<dim3(128, 2), 256, 0, stream>>>(
        xhi, xlo, KXP, WinThi, WinTlo, b_in, b_in, b_in,
        lin1, lin1, lin1, HD, lin1hi, lin1lo, HD, HD, g);
    // fused Q/K/V projections (N=768)
    gemm_f16s<0, 1, 0, 1><<<dim3(128, 6), 256, 0, stream>>>(
        lin1hi, lin1lo, HD, Wqkvhi, Wqkvlo, bq, bk, bv,
        Qb, Ks + (long)ci * RR * HD, Vs + (long)ci * RR * HD, HD,
        nullptr, nullptr, HD, 768, g);
    // attention over channels 0..ci
    switch (ci) {
      case 0: attn_k<1><<<4096, 256, 0, stream>>>(Qb, Ks, Vs, ctxhi, ctxlo, g); break;
      case 1: attn_k<2><<<4096, 256, 0, stream>>>(Qb, Ks, Vs, ctxhi, ctxlo, g); break;
      case 2: attn_k<3><<<4096, 256, 0, stream>>>(Qb, Ks, Vs, ctxhi, ctxlo, g); break;
      case 3: attn_k<4><<<4096, 256, 0, stream>>>(Qb, Ks, Vs, ctxhi, ctxlo, g); break;
      case 4: attn_k<5><<<4096, 256, 0, stream>>>(Qb, Ks, Vs, ctxhi, ctxlo, g); break;
      case 5: attn_k<6><<<4096, 256, 0, stream>>>(Qb, Ks, Vs, ctxhi, ctxlo, g); break;
      case 6: attn_k<7><<<4096, 256, 0, stream>>>(Qb, Ks, Vs, ctxhi, ctxlo, g); break;
      default: attn_k<8><<<4096, 256, 0, stream>>>(Qb, Ks, Vs, ctxhi, ctxlo, g); break;
    }
    // h1 = LN(lin1 + ctx @ Wo + bo)
    gemm_f16s<0, 1, 0, 0><<<dim3(128, 2), 256, 0, stream>>>(
        ctxhi, ctxlo, HD, WoThi, WoTlo, bo, bo, bo,
        gb, gb, gb, HD, nullptr, nullptr, HD, HD, g);
    ln_res_k<1><<<2048, 256, 0, stream>>>(lin1, gb, ln1g, ln1b, h1, h1hi, h1lo, g);
    // hh = LN(h1 + relu(h1@Wf1+bf1)@Wf2+bf2)
    gemm_f16s<1, 0, 1, 0><<<dim3(128, 4), 256, 0, stream>>>(
        h1hi, h1lo, HD, Wf1Thi, Wf1Tlo, bf1, bf1, bf1,
        nullptr, nullptr, nullptr, WN, t1hi, t1lo, WN, WN, g);
    gemm_f16s<0, 1, 0, 0><<<dim3(128, 2), 256, 0, stream>>>(
        t1hi, t1lo, WN, Wf2Thi, Wf2Tlo, bf2, bf2, bf2,
        gb, gb, gb, HD, nullptr, nullptr, HD, HD, g);
    ln_res_k<1><<<2048, 256, 0, stream>>>(h1, gb, ln2g, ln2b, hh, hhhi, hhlo, g);
    // ponder head + ACT state update
    if (ci < CH - 1)
      gemm_f16s<1, 1, 0, 0><<<dim3(128, 1), 256, 0, stream>>>(
          hhhi, hhlo, HD, Ws1Thi, Ws1Tlo, bs1, bs1, bs1,
          s1, s1, s1, HF, nullptr, nullptr, HD, HF, g);
    act_k<<<2048, 256, 0, stream>>>(s1, Ws2, bs2, psa, psb, hh, cum, rem, still,
                                    pc, outb, outhi, outlo,
                                    (ci == CH - 1) ? 1 : 0, g, flags + ci);
    gate_k<<<1, 1, 0, stream>>>(gate + ci, gate + ci + 1, flags + ci);
  }
  // encoder_out = relu(out @ W_out + b_out)
  gemm_f16s<1, 1, 0, 0><<<dim3(128, 3), 256, 0, stream>>>(
      outhi, outlo, HD, WoutThi, WoutTlo, b_out, b_out, b_out,
      (float*)d_out, (float*)d_out, (float*)d_out, FB,
      nullptr, nullptr, HD, FB, nullptr);
  pc_copy_k<<<64, 256, 0, stream>>>(pc, (float*)d_out + (long)RR * FB);
}

// Round 4
// 965.311 us; speedup vs baseline: 1.6697x; 1.0288x over previous
//
#include <hip/hip_runtime.h>
#include <hip/hip_bf16.h>
#include <math.h>

typedef _Float16 f16;
typedef _Float16 f16x8 __attribute__((ext_vector_type(8)));
typedef float f32x16 __attribute__((ext_vector_type(16)));

constexpr int CH = 8;      // channels
constexpr int TT = 2048;   // time frames
constexpr int FB = 257;    // freq bins
constexpr int HD = 256;    // hidden
constexpr int DHD = 64;    // head dim
constexpr int WN = 512;    // ffn dim
constexpr int HF = 128;    // H/2
constexpr int RR = 8 * TT; // 16384 rows
constexpr int KXP = 288;   // padded K for x / W_in (257 -> 288 = 9*32)

// ---------------------------------------------------------------------------
// Split-f16 MFMA GEMM:  C = act(A @ W + bias).
// A: [16384][K] split f16 hi/lo, or (XSRC) raw fp32 x slice split on the fly.
// W: transposed-split [Npad][K] (hi,lo). Block 128x128, BK=32, 4 waves (2x2),
// wave tile 64x64 of 32x32x16 MFMA frags. 3 MFMAs per frag pair:
// Al*Wh + Ah*Wl + Ah*Wh (error ~2^-22 rel). Early-exit on dead ACT iter.
// All 16 frag ds_reads hoisted before the 24 MFMAs (single-wave lgkm batch).
// ---------------------------------------------------------------------------
template<int ACT, int WF32, int WF16, int QKV, int XSRC>
__global__ __launch_bounds__(256) void gemm_f16s(
    const f16* __restrict__ Ahi, const f16* __restrict__ Alo, int K,
    const float* __restrict__ Axf, long agrp,
    const f16* __restrict__ Bhi, const f16* __restrict__ Blo,
    const float* __restrict__ bias, const float* __restrict__ bias1,
    const float* __restrict__ bias2,
    float* __restrict__ C0, float* __restrict__ C1, float* __restrict__ C2,
    int ldc, f16* __restrict__ Chi, f16* __restrict__ Clo, int ldf,
    int Nreal, const int* __restrict__ alive)
{
  if (alive && *alive == 0) return;
  __shared__ f16 As[2][128][40];   // [hi/lo][row][k] (+8 f16 pad)
  __shared__ f16 Bs[2][128][40];
  const int tid = threadIdx.x;
  const int m0 = blockIdx.x * 128;
  const int n0 = blockIdx.y * 128;
  const int q = tid & 3, r = tid >> 2;          // staging: 4 lanes/row
  const int lane = tid & 63, wave = tid >> 6;
  const int wm = wave & 1, wn = wave >> 1;      // 2x2 wave grid
  const int lr = lane & 31, lg = lane >> 5;     // frag row/col, k-group

  f32x16 acc[2][2];
  #pragma unroll
  for (int mf = 0; mf < 2; mf++)
    #pragma unroll
    for (int nf = 0; nf < 2; nf++)
      #pragma unroll
      for (int g = 0; g < 16; g++) acc[mf][nf][g] = 0.f;

  f16x8 sAh0, sAh1, sAl0, sAl1, sBh0, sBh1, sBl0, sBl1;
  const long aoff = (long)(m0 + r) * K + q * 8;
  const long boff = (long)(n0 + r) * K + q * 8;
  const long hstep = (long)64 * K;
  const float* xR0 = nullptr;
  const float* xR1 = nullptr;
  if constexpr (XSRC) {
    const int r0 = m0 + r, r1 = m0 + r + 64;
    xR0 = Axf + ((long)(r0 >> 11)) * agrp + (long)(r0 & 2047) * FB;
    xR1 = Axf + ((long)(r1 >> 11)) * agrp + (long)(r1 & 2047) * FB;
  }

  auto loadA = [&](int k0) {
    if constexpr (XSRC) {
      float a0[8], a1[8];
      #pragma unroll
      for (int j = 0; j < 8; j++) {
        const int k = k0 + q * 8 + j;
        a0[j] = (k < FB) ? xR0[k] : 0.f;
        a1[j] = (k < FB) ? xR1[k] : 0.f;
      }
      #pragma unroll
      for (int j = 0; j < 8; j++) {
        const f16 h0 = (f16)a0[j]; sAh0[j] = h0; sAl0[j] = (f16)(a0[j] - (float)h0);
        const f16 h1 = (f16)a1[j]; sAh1[j] = h1; sAl1[j] = (f16)(a1[j] - (float)h1);
      }
    } else {
      const long a = aoff + k0;
      sAh0 = *(const f16x8*)(Ahi + a);  sAh1 = *(const f16x8*)(Ahi + a + hstep);
      sAl0 = *(const f16x8*)(Alo + a);  sAl1 = *(const f16x8*)(Alo + a + hstep);
    }
  };
  auto loadB = [&](int k0) {
    const long b = boff + k0;
    sBh0 = *(const f16x8*)(Bhi + b);  sBh1 = *(const f16x8*)(Bhi + b + hstep);
    sBl0 = *(const f16x8*)(Blo + b);  sBl1 = *(const f16x8*)(Blo + b + hstep);
  };

  loadA(0);
  loadB(0);

  for (int k0 = 0; k0 < K; k0 += 32) {
    __syncthreads();   // previous MAC readers done before overwrite
    *(f16x8*)&As[0][r][q * 8] = sAh0;  *(f16x8*)&As[0][r + 64][q * 8] = sAh1;
    *(f16x8*)&As[1][r][q * 8] = sAl0;  *(f16x8*)&As[1][r + 64][q * 8] = sAl1;
    *(f16x8*)&Bs[0][r][q * 8] = sBh0;  *(f16x8*)&Bs[0][r + 64][q * 8] = sBh1;
    *(f16x8*)&Bs[1][r][q * 8] = sBl0;  *(f16x8*)&Bs[1][r + 64][q * 8] = sBl1;
    __syncthreads();
    if (k0 + 32 < K) {   // prefetch next tile; hides under frag reads + MFMAs
      loadA(k0 + 32);
      loadB(k0 + 32);
    }
    // hoisted fragment reads: 16 ds_read_b128 batched, then 24 MFMAs
    f16x8 ah[2][2], al[2][2], bh[2][2], bl[2][2];
    #pragma unroll
    for (int kh = 0; kh < 2; kh++) {
      const int kk = kh * 16 + lg * 8;
      #pragma unroll
      for (int mf = 0; mf < 2; mf++) {
        const int mm = wm * 64 + mf * 32 + lr;
        ah[kh][mf] = *(const f16x8*)&As[0][mm][kk];
        al[kh][mf] = *(const f16x8*)&As[1][mm][kk];
      }
      #pragma unroll
      for (int nf = 0; nf < 2; nf++) {
        const int nn = wn * 64 + nf * 32 + lr;
        bh[kh][nf] = *(const f16x8*)&Bs[0][nn][kk];
        bl[kh][nf] = *(const f16x8*)&Bs[1][nn][kk];
      }
    }
    #pragma unroll
    for (int kh = 0; kh < 2; kh++)
      #pragma unroll
      for (int mf = 0; mf < 2; mf++)
        #pragma unroll
        for (int nf = 0; nf < 2; nf++) {
          acc[mf][nf] = __builtin_amdgcn_mfma_f32_32x32x16_f16(al[kh][mf], bh[kh][nf], acc[mf][nf], 0, 0, 0);
          acc[mf][nf] = __builtin_amdgcn_mfma_f32_32x32x16_f16(ah[kh][mf], bl[kh][nf], acc[mf][nf], 0, 0, 0);
          acc[mf][nf] = __builtin_amdgcn_mfma_f32_32x32x16_f16(ah[kh][mf], bh[kh][nf], acc[mf][nf], 0, 0, 0);
        }
  }

  // epilogue: C/D layout col=lane&31, row=(g&3)+8*(g>>2)+4*(lane>>5)
  #pragma unroll
  for (int mf = 0; mf < 2; mf++)
    #pragma unroll
    for (int nf = 0; nf < 2; nf++) {
      const int col = n0 + wn * 64 + nf * 32 + lr;
      const float* bp = bias;
      float* Cp = C0;
      int cc = col;
      if (QKV) {
        const int sel = col >> 8;
        cc = col & 255;
        Cp = sel == 0 ? C0 : (sel == 1 ? C1 : C2);
        bp = sel == 0 ? bias : (sel == 1 ? bias1 : bias2);
      }
      const float bb = (col < Nreal) ? bp[cc] : 0.f;
      #pragma unroll
      for (int g = 0; g < 16; g++) {
        const long row = m0 + wm * 64 + mf * 32 + (g & 3) + 8 * (g >> 2) + 4 * lg;
        float v = acc[mf][nf][g] + bb;
        if (ACT) v = fmaxf(v, 0.f);
        if (col < Nreal) {
          if (WF32) Cp[row * (long)ldc + cc] = v;
          if (WF16) {
            const f16 hi = (f16)v;
            Chi[row * (long)ldf + col] = hi;
            Clo[row * (long)ldf + col] = (f16)(v - (float)hi);
          }
        }
      }
    }
}

// ---------------------------------------------------------------------------
// Weight transpose + f16 hi/lo split (one-time). blockIdx.y selects target.
// ---------------------------------------------------------------------------
__global__ __launch_bounds__(256) void wsplit_k(
    const float* __restrict__ W_in, const float* __restrict__ Wq,
    const float* __restrict__ Wk, const float* __restrict__ Wv,
    const float* __restrict__ Wo, const float* __restrict__ Wf1,
    const float* __restrict__ Wf2, const float* __restrict__ Ws1,
    const float* __restrict__ Wout,
    f16* __restrict__ WinThi, f16* __restrict__ WinTlo,
    f16* __restrict__ Wqkvhi, f16* __restrict__ Wqkvlo,
    f16* __restrict__ WoThi,  f16* __restrict__ WoTlo,
    f16* __restrict__ Wf1Thi, f16* __restrict__ Wf1Tlo,
    f16* __restrict__ Wf2Thi, f16* __restrict__ Wf2Tlo,
    f16* __restrict__ Ws1Thi, f16* __restrict__ Ws1Tlo,
    f16* __restrict__ WoutThi, f16* __restrict__ WoutTlo)
{
  const int y = blockIdx.y;
  const long idx = (long)blockIdx.x * 256 + threadIdx.x;
  int Npad, Kpad, Ksrc;
  f16 *dh, *dl;
  switch (y) {
    case 0: Npad = 256; Kpad = 288; Ksrc = 257; dh = WinThi;  dl = WinTlo;  break;
    case 1: Npad = 768; Kpad = 256; Ksrc = 256; dh = Wqkvhi;  dl = Wqkvlo;  break;
    case 2: Npad = 256; Kpad = 256; Ksrc = 256; dh = WoThi;   dl = WoTlo;   break;
    case 3: Npad = 512; Kpad = 256; Ksrc = 256; dh = Wf1Thi;  dl = Wf1Tlo;  break;
    case 4: Npad = 256; Kpad = 512; Ksrc = 512; dh = Wf2Thi;  dl = Wf2Tlo;  break;
    case 5: Npad = 128; Kpad = 256; Ksrc = 256; dh = Ws1Thi;  dl = Ws1Tlo;  break;
    default: Npad = 384; Kpad = 256; Ksrc = 256; dh = WoutThi; dl = WoutTlo; break;
  }
  if (idx >= (long)Npad * Kpad) return;
  const int n = (int)(idx / Kpad), k = (int)(idx % Kpad);
  float v = 0.f;
  if (k < Ksrc) {
    switch (y) {
      case 0: v = W_in[(long)k * 256 + n]; break;
      case 1: { const int sel = n >> 8;
                const float* s = sel == 0 ? Wq : (sel == 1 ? Wk : Wv);
                v = s[(long)k * 256 + (n & 255)]; } break;
      case 2: v = Wo[(long)k * 256 + n]; break;
      case 3: v = Wf1[(long)k * 512 + n]; break;
      case 4: v = Wf2[(long)k * 256 + n]; break;
      case 5: v = Ws1[(long)k * 128 + n]; break;
      default: v = (n < 257) ? Wout[(long)k * 257 + n] : 0.f; break;
    }
  }
  const f16 hi = (f16)v;
  dh[idx] = hi;
  dl[idx] = (f16)(v - (float)hi);
}

// ---------------------------------------------------------------------------
// Per-time-frame attention over channels; writes ctx as f16 hi/lo.
// ---------------------------------------------------------------------------
template<int NCc>
__global__ __launch_bounds__(256) void attn_k(
    const float* __restrict__ Q, const float* __restrict__ Ksp,
    const float* __restrict__ Vsp, f16* __restrict__ chi,
    f16* __restrict__ clo, const int* __restrict__ alive)
{
  if (alive && *alive == 0) return;
  const int w = threadIdx.x >> 6;   // head
  const int l = threadIdx.x & 63;   // dh lane
  for (int rr = 0; rr < 4; rr++) {
    const long r = (long)blockIdx.x * 4 + rr;
    const float qv = Q[r * HD + w * DHD + l];
    float sc[NCc];
    #pragma unroll
    for (int c = 0; c < NCc; c++) {
      float p = qv * Ksp[((long)c * RR + r) * HD + w * DHD + l];
      #pragma unroll
      for (int s = 32; s > 0; s >>= 1) p += __shfl_xor(p, s, 64);
      sc[c] = p * 0.125f;   // 1/sqrt(64)
    }
    float m = sc[0];
    #pragma unroll
    for (int c = 1; c < NCc; c++) m = fmaxf(m, sc[c]);
    float a[NCc];
    float den = 0.f;
    #pragma unroll
    for (int c = 0; c < NCc; c++) { a[c] = expf(sc[c] - m); den += a[c]; }
    float cv = 0.f;
    #pragma unroll
    for (int c = 0; c < NCc; c++)
      cv = fmaf(a[c] / den, Vsp[((long)c * RR + r) * HD + w * DHD + l], cv);
    const f16 hi = (f16)cv;
    chi[r * HD + w * DHD + l] = hi;
    clo[r * HD + w * DHD + l] = (f16)(cv - (float)hi);
  }
}

// ---------------------------------------------------------------------------
// O = LayerNorm(X + Y) * g + b over H=256; optional f16 hi/lo output.
// Joint (sum, sumsq) reduction; ping-pong LDS slots -> 1 barrier per row.
// ---------------------------------------------------------------------------
template<int WF16>
__global__ __launch_bounds__(256) void ln_res_k(
    const float* __restrict__ X, const float* __restrict__ Y,
    const float* __restrict__ g, const float* __restrict__ b,
    float* __restrict__ O, f16* __restrict__ Ohi, f16* __restrict__ Olo,
    const int* __restrict__ alive)
{
  if (alive && *alive == 0) return;
  __shared__ float red[2][8];
  const int tid = threadIdx.x;
  const int w = tid >> 6;
  for (int rr = 0; rr < 8; rr++) {
    const int p = rr & 1;
    const long r = (long)blockIdx.x * 8 + rr;
    const float v = X[r * HD + tid] + Y[r * HD + tid];
    float s = v, sq = v * v;
    #pragma unroll
    for (int i = 32; i > 0; i >>= 1) {
      s += __shfl_xor(s, i, 64);
      sq += __shfl_xor(sq, i, 64);
    }
    if ((tid & 63) == 0) { red[p][w] = s; red[p][4 + w] = sq; }
    __syncthreads();
    const float mean = (red[p][0] + red[p][1] + red[p][2] + red[p][3]) * (1.f / HD);
    const float ex2 = (red[p][4] + red[p][5] + red[p][6] + red[p][7]) * (1.f / HD);
    const float var = ex2 - mean * mean;
    const float inv = 1.f / sqrtf(var + 1e-5f);
    const float o = (v - mean) * inv * g[tid] + b[tid];
    O[r * HD + tid] = o;
    if (WF16) {
      const f16 hi = (f16)o;
      Ohi[r * HD + tid] = hi;
      Olo[r * HD + tid] = (f16)(o - (float)hi);
    }
  }
}

// ---------------------------------------------------------------------------
// ACT ponder update (exact reference formulas). Writes out fp32 + f16 hi/lo.
// Sets myFlag=1 if any row still active after update (next iter's liveness).
// ---------------------------------------------------------------------------
__global__ __launch_bounds__(256) void act_k(
    const float* __restrict__ s1, const float* __restrict__ Ws2,
    const float* __restrict__ bs2, const float* __restrict__ psa,
    const float* __restrict__ psb, const float* __restrict__ hh,
    float* __restrict__ cum, float* __restrict__ rem,
    float* __restrict__ still, float* __restrict__ pc,
    float* __restrict__ out, f16* __restrict__ outhi, f16* __restrict__ outlo,
    int lastIter, const int* __restrict__ alive, int* __restrict__ myFlag)
{
  if (alive && *alive == 0) return;
  __shared__ float red[2][4];
  const int tid = threadIdx.x;
  const int w = tid >> 6;
  for (int rr = 0; rr < 8; rr++) {
    const int p = rr & 1;
    const long r = (long)blockIdx.x * 8 + rr;
    float curv;
    if (!lastIter) {
      float pv = (tid < HF) ? s1[r * HF + tid] * Ws2[tid] : 0.f;
      #pragma unroll
      for (int i = 32; i > 0; i >>= 1) pv += __shfl_xor(pv, i, 64);
      if ((tid & 63) == 0) red[p][w] = pv;
      __syncthreads();
      const float s = red[p][0] + red[p][1] + red[p][2] + red[p][3] + bs2[0];
      const float z = (s - psa[0]) / (psb[0] + 1e-8f);
      curv = 1.f / (1.f + expf(-z));
    } else {
      curv = 1.f;
    }
    const float cu = cum[r], re = rem[r], st = still[r], pp = pc[r];
    const float cum_n = cu + curv * st;
    float pc_n = pp + st;
    const float still_n = (cum_n < 0.9999f) ? 1.f : 0.f;
    const float wgt = curv * still_n + re * (1.f - still_n);
    const float newv = out[r * HD + tid] + hh[r * HD + tid] * wgt;
    out[r * HD + tid] = newv;
    const f16 hi = (f16)newv;
    outhi[r * HD + tid] = hi;
    outlo[r * HD + tid] = (f16)(newv - (float)hi);
    const float rem_n = re - curv * still_n;
    pc_n += rem_n * (1.f - still_n);
    if (tid == 0) {
      cum[r] = cum_n; rem[r] = rem_n; still[r] = still_n; pc[r] = pc_n;
      if (still_n > 0.5f) *myFlag = 1;
    }
  }
}

__global__ __launch_bounds__(256) void init_k(
    float* out, float* cum, float* rem, float* still, float* pc, int* flags)
{
  const long gid = (long)blockIdx.x * 256 + threadIdx.x;
  const long n = (long)RR * HD;
  for (long i = gid; i < n; i += (long)gridDim.x * 256) out[i] = 0.f;
  if (gid < RR) { cum[gid] = 0.f; rem[gid] = 1.f; still[gid] = 1.f; pc[gid] = 0.f; }
  if (gid < 8) flags[gid] = 0;
}

__global__ __launch_bounds__(256) void pc_copy_k(const float* pc, float* o) {
  const int i = blockIdx.x * 256 + threadIdx.x;
  o[i] = pc[i];
}

// ---------------------------------------------------------------------------
extern "C" void kernel_launch(void* const* d_in, const int* in_sizes, int n_in,
                              void* d_out, int out_size, void* d_ws, size_t ws_size,
                              hipStream_t stream) {
  const float* x    = (const float*)d_in[0];
  const float* W_in = (const float*)d_in[1];
  const float* b_in = (const float*)d_in[2];
  const float* W_out= (const float*)d_in[3];
  const float* b_out= (const float*)d_in[4];
  const float* Wq   = (const float*)d_in[5];
  const float* bq   = (const float*)d_in[6];
  const float* Wk   = (const float*)d_in[7];
  const float* bk   = (const float*)d_in[8];
  const float* Wv   = (const float*)d_in[9];
  const float* bv   = (const float*)d_in[10];
  const float* Wo   = (const float*)d_in[11];
  const float* bo   = (const float*)d_in[12];
  const float* ln1g = (const float*)d_in[13];
  const float* ln1b = (const float*)d_in[14];
  const float* Wf1  = (const float*)d_in[15];
  const float* bf1  = (const float*)d_in[16];
  const float* Wf2  = (const float*)d_in[17];
  const float* bf2  = (const float*)d_in[18];
  const float* ln2g = (const float*)d_in[19];
  const float* ln2b = (const float*)d_in[20];
  const float* Ws1  = (const float*)d_in[21];
  const float* bs1  = (const float*)d_in[22];
  const float* Ws2  = (const float*)d_in[23];
  const float* bs2  = (const float*)d_in[24];
  const float* psa  = (const float*)d_in[25];
  const float* psb  = (const float*)d_in[26];

  float* ws = (float*)d_ws;
  long off = 0;
  auto alloc = [&](long n) { float* p = ws + off; off += n; return p; };
  float* Ks   = alloc((long)CH * RR * HD);
  float* Vs   = alloc((long)CH * RR * HD);
  float* lin1 = alloc((long)RR * HD);
  float* Qb   = alloc((long)RR * HD);
  float* gb   = alloc((long)RR * HD);
  float* h1   = alloc((long)RR * HD);
  float* hh   = alloc((long)RR * HD);
  float* outb = alloc((long)RR * HD);
  float* s1   = alloc((long)RR * HF);
  f16* lin1hi = (f16*)alloc((long)RR * HD / 2);
  f16* lin1lo = (f16*)alloc((long)RR * HD / 2);
  f16* ctxhi  = (f16*)alloc((long)RR * HD / 2);
  f16* ctxlo  = (f16*)alloc((long)RR * HD / 2);
  f16* h1hi   = (f16*)alloc((long)RR * HD / 2);
  f16* h1lo   = (f16*)alloc((long)RR * HD / 2);
  f16* hhhi   = (f16*)alloc((long)RR * HD / 2);
  f16* hhlo   = (f16*)alloc((long)RR * HD / 2);
  f16* t1hi   = (f16*)alloc((long)RR * WN / 2);
  f16* t1lo   = (f16*)alloc((long)RR * WN / 2);
  f16* outhi  = (f16*)alloc((long)RR * HD / 2);
  f16* outlo  = (f16*)alloc((long)RR * HD / 2);
  f16* WinThi = (f16*)alloc(256 * 288 / 2);
  f16* WinTlo = (f16*)alloc(256 * 288 / 2);
  f16* Wqkvhi = (f16*)alloc(768 * 256 / 2);
  f16* Wqkvlo = (f16*)alloc(768 * 256 / 2);
  f16* WoThi  = (f16*)alloc(256 * 256 / 2);
  f16* WoTlo  = (f16*)alloc(256 * 256 / 2);
  f16* Wf1Thi = (f16*)alloc(512 * 256 / 2);
  f16* Wf1Tlo = (f16*)alloc(512 * 256 / 2);
  f16* Wf2Thi = (f16*)alloc(256 * 512 / 2);
  f16* Wf2Tlo = (f16*)alloc(256 * 512 / 2);
  f16* Ws1Thi = (f16*)alloc(128 * 256 / 2);
  f16* Ws1Tlo = (f16*)alloc(128 * 256 / 2);
  f16* WoutThi= (f16*)alloc(384 * 256 / 2);
  f16* WoutTlo= (f16*)alloc(384 * 256 / 2);
  float* cum  = alloc(RR);
  float* rem  = alloc(RR);
  float* still= alloc(RR);
  float* pc   = alloc(RR);
  int* flags  = (int*)alloc(8);

  init_k<<<2048, 256, 0, stream>>>(outb, cum, rem, still, pc, flags);
  wsplit_k<<<dim3(768, 7), 256, 0, stream>>>(
      W_in, Wq, Wk, Wv, Wo, Wf1, Wf2, Ws1, W_out,
      WinThi, WinTlo, Wqkvhi, Wqkvlo, WoThi, WoTlo, Wf1Thi, Wf1Tlo,
      Wf2Thi, Wf2Tlo, Ws1Thi, Ws1Tlo, WoutThi, WoutTlo);

  for (int ci = 0; ci < CH; ci++) {
    // liveness: iteration ci runs iff iteration ci-1 saw an unhalted row
    const int* al = (ci == 0) ? nullptr : (flags + ci - 1);
    // lin1 = relu(x[:,ci] @ W_in + b_in), x read fp32 + split on the fly
    gemm_f16s<1, 1, 1, 0, 1><<<dim3(128, 2), 256, 0, stream>>>(
        nullptr, nullptr, KXP, x + (long)ci * TT * FB, (long)CH * TT * FB,
        WinThi, WinTlo, b_in, b_in, b_in,
        lin1, lin1, lin1, HD, lin1hi, lin1lo, HD, HD, al);
    // fused Q/K/V projections (N=768)
    gemm_f16s<0, 1, 0, 1, 0><<<dim3(128, 6), 256, 0, stream>>>(
        lin1hi, lin1lo, HD, nullptr, 0, Wqkvhi, Wqkvlo, bq, bk, bv,
        Qb, Ks + (long)ci * RR * HD, Vs + (long)ci * RR * HD, HD,
        nullptr, nullptr, HD, 768, al);
    // attention over channels 0..ci
    switch (ci) {
      case 0: attn_k<1><<<4096, 256, 0, stream>>>(Qb, Ks, Vs, ctxhi, ctxlo, al); break;
      case 1: attn_k<2><<<4096, 256, 0, stream>>>(Qb, Ks, Vs, ctxhi, ctxlo, al); break;
      case 2: attn_k<3><<<4096, 256, 0, stream>>>(Qb, Ks, Vs, ctxhi, ctxlo, al); break;
      case 3: attn_k<4><<<4096, 256, 0, stream>>>(Qb, Ks, Vs, ctxhi, ctxlo, al); break;
      case 4: attn_k<5><<<4096, 256, 0, stream>>>(Qb, Ks, Vs, ctxhi, ctxlo, al); break;
      case 5: attn_k<6><<<4096, 256, 0, stream>>>(Qb, Ks, Vs, ctxhi, ctxlo, al); break;
      case 6: attn_k<7><<<4096, 256, 0, stream>>>(Qb, Ks, Vs, ctxhi, ctxlo, al); break;
      default: attn_k<8><<<4096, 256, 0, stream>>>(Qb, Ks, Vs, ctxhi, ctxlo, al); break;
    }
    // h1 = LN(lin1 + ctx @ Wo + bo)
    gemm_f16s<0, 1, 0, 0, 0><<<dim3(128, 2), 256, 0, stream>>>(
        ctxhi, ctxlo, HD, nullptr, 0, WoThi, WoTlo, bo, bo, bo,
        gb, gb, gb, HD, nullptr, nullptr, HD, HD, al);
    ln_res_k<1><<<2048, 256, 0, stream>>>(lin1, gb, ln1g, ln1b, h1, h1hi, h1lo, al);
    // hh = LN(h1 + relu(h1@Wf1+bf1)@Wf2+bf2)
    gemm_f16s<1, 0, 1, 0, 0><<<dim3(128, 4), 256, 0, stream>>>(
        h1hi, h1lo, HD, nullptr, 0, Wf1Thi, Wf1Tlo, bf1, bf1, bf1,
        nullptr, nullptr, nullptr, WN, t1hi, t1lo, WN, WN, al);
    gemm_f16s<0, 1, 0, 0, 0><<<dim3(128, 2), 256, 0, stream>>>(
        t1hi, t1lo, WN, nullptr, 0, Wf2Thi, Wf2Tlo, bf2, bf2, bf2,
        gb, gb, gb, HD, nullptr, nullptr, HD, HD, al);
    ln_res_k<1><<<2048, 256, 0, stream>>>(h1, gb, ln2g, ln2b, hh, hhhi, hhlo, al);
    // ponder head + ACT state update
    if (ci < CH - 1)
      gemm_f16s<1, 1, 0, 0, 0><<<dim3(128, 1), 256, 0, stream>>>(
          hhhi, hhlo, HD, nullptr, 0, Ws1Thi, Ws1Tlo, bs1, bs1, bs1,
          s1, s1, s1, HF, nullptr, nullptr, HD, HF, al);
    act_k<<<2048, 256, 0, stream>>>(s1, Ws2, bs2, psa, psb, hh, cum, rem, still,
                                    pc, outb, outhi, outlo,
                                    (ci == CH - 1) ? 1 : 0, al, flags + ci);
  }
  // encoder_out = relu(out @ W_out + b_out)
  gemm_f16s<1, 1, 0, 0, 0><<<dim3(128, 3), 256, 0, stream>>>(
      outhi, outlo, HD, nullptr, 0, WoutThi, WoutTlo, b_out, b_out, b_out,
      (float*)d_out, (float*)d_out, (float*)d_out, FB,
      nullptr, nullptr, HD, FB, nullptr);
  pc_copy_k<<<64, 256, 0, stream>>>(pc, (float*)d_out + (long)RR * FB);
}

// Round 5
// 950.496 us; speedup vs baseline: 1.6957x; 1.0156x over previous
//
#include <hip/hip_runtime.h>
#include <hip/hip_bf16.h>
#include <math.h>

typedef _Float16 f16;
typedef _Float16 f16x8 __attribute__((ext_vector_type(8)));
typedef float f32x16 __attribute__((ext_vector_type(16)));

constexpr int CH = 8;      // channels
constexpr int TT = 2048;   // time frames
constexpr int FB = 257;    // freq bins
constexpr int HD = 256;    // hidden
constexpr int DHD = 64;    // head dim
constexpr int WN = 512;    // ffn dim
constexpr int HF = 128;    // H/2
constexpr int RR = 8 * TT; // 16384 rows
constexpr int KXP = 288;   // padded K for x / W_in (257 -> 288 = 9*32)

// ---------------------------------------------------------------------------
// Split-f16 MFMA GEMM v2:  C = act(A @ W + bias).
// Tile 128x64, 4 waves, wave tile 32x64 (2 N-frags of 32x32x16).
// A staged in LDS (double-buffered, ONE barrier/k-step); B read directly from
// global in packed frag layout [N/32][K/8][hi|lo][32][8] (coalesced 512B, L2).
// 3 MFMAs per frag pair: Al*Bh + Ah*Bl + Ah*Bh (error ~2^-22 rel).
// ---------------------------------------------------------------------------
template<int ACT, int WF32, int WF16, int QKV, int XSRC>
__global__ __launch_bounds__(256, 2) void gemm2(
    const f16* __restrict__ Ahi, const f16* __restrict__ Alo, int K,
    const float* __restrict__ Axf, long agrp,
    const f16* __restrict__ Bp,
    const float* __restrict__ bias, const float* __restrict__ bias1,
    const float* __restrict__ bias2,
    float* __restrict__ C0, float* __restrict__ C1, float* __restrict__ C2,
    int ldc, f16* __restrict__ Chi, f16* __restrict__ Clo, int ldf,
    int Nreal, const int* __restrict__ alive)
{
  if (alive && *alive == 0) return;
  __shared__ f16 As[2][2][128][40];   // [dbuf][hi/lo][row][k] (+8 f16 pad)
  const int tid = threadIdx.x;
  const int m0 = blockIdx.x * 128;
  const int n0 = blockIdx.y * 64;
  const int q = tid & 3, r = tid >> 2;          // staging: 4 lanes/row
  const int lane = tid & 63, wm = tid >> 6;     // wave = M-slice
  const int lr = lane & 31, lg = lane >> 5;
  const int nb0 = n0 >> 5, kd8 = K >> 3;

  f32x16 acc[2];
  #pragma unroll
  for (int nf = 0; nf < 2; nf++)
    #pragma unroll
    for (int g = 0; g < 16; g++) acc[nf][g] = 0.f;

  const long aoff = (long)(m0 + r) * K + q * 8;
  const long hstep = (long)64 * K;
  const float* xR0 = nullptr;
  const float* xR1 = nullptr;
  if constexpr (XSRC) {
    const int r0 = m0 + r, r1 = r0 + 64;
    xR0 = Axf + (long)(r0 >> 11) * agrp + (long)(r0 & 2047) * FB;
    xR1 = Axf + (long)(r1 >> 11) * agrp + (long)(r1 & 2047) * FB;
  }

  // A: [0]=hi row r, [1]=hi row r+64, [2]=lo row r, [3]=lo row r+64
  auto loadA = [&](f16x8* A, int k0) {
    if constexpr (XSRC) {
      float a0[8], a1[8];
      #pragma unroll
      for (int j = 0; j < 8; j++) {
        const int k = k0 + q * 8 + j;
        a0[j] = (k < FB) ? xR0[k] : 0.f;
        a1[j] = (k < FB) ? xR1[k] : 0.f;
      }
      #pragma unroll
      for (int j = 0; j < 8; j++) {
        const f16 h0 = (f16)a0[j]; A[0][j] = h0; A[2][j] = (f16)(a0[j] - (float)h0);
        const f16 h1 = (f16)a1[j]; A[1][j] = h1; A[3][j] = (f16)(a1[j] - (float)h1);
      }
    } else {
      const long a = aoff + k0;
      A[0] = *(const f16x8*)(Ahi + a);  A[1] = *(const f16x8*)(Ahi + a + hstep);
      A[2] = *(const f16x8*)(Alo + a);  A[3] = *(const f16x8*)(Alo + a + hstep);
    }
  };
  auto loadB = [&](f16x8 B[2][2][2], int k0) {
    const int kb = (k0 >> 3) + lg;
    #pragma unroll
    for (int kh = 0; kh < 2; kh++)
      #pragma unroll
      for (int nf = 0; nf < 2; nf++)
        #pragma unroll
        for (int hl = 0; hl < 2; hl++)
          B[kh][nf][hl] = *(const f16x8*)(Bp +
              ((long)((nb0 + nf) * kd8 + kb + kh * 2) * 512 + hl * 256 + lr * 8));
  };
  auto kstep = [&](f16x8* SA, f16x8 SB[2][2][2], f16x8* TA, f16x8 TB[2][2][2],
                   int k0, int d) {
    *(f16x8*)&As[d][0][r][q * 8]      = SA[0];
    *(f16x8*)&As[d][0][r + 64][q * 8] = SA[1];
    *(f16x8*)&As[d][1][r][q * 8]      = SA[2];
    *(f16x8*)&As[d][1][r + 64][q * 8] = SA[3];
    __syncthreads();
    if (k0 + 32 < K) { loadA(TA, k0 + 32); loadB(TB, k0 + 32); }
    f16x8 fa[2][2];   // [kh][hi/lo]
    #pragma unroll
    for (int kh = 0; kh < 2; kh++)
      #pragma unroll
      for (int hl = 0; hl < 2; hl++)
        fa[kh][hl] = *(const f16x8*)&As[d][hl][wm * 32 + lr][kh * 16 + lg * 8];
    #pragma unroll
    for (int kh = 0; kh < 2; kh++)
      #pragma unroll
      for (int nf = 0; nf < 2; nf++) {
        acc[nf] = __builtin_amdgcn_mfma_f32_32x32x16_f16(fa[kh][1], SB[kh][nf][0], acc[nf], 0, 0, 0);
        acc[nf] = __builtin_amdgcn_mfma_f32_32x32x16_f16(fa[kh][0], SB[kh][nf][1], acc[nf], 0, 0, 0);
        acc[nf] = __builtin_amdgcn_mfma_f32_32x32x16_f16(fa[kh][0], SB[kh][nf][0], acc[nf], 0, 0, 0);
      }
  };

  f16x8 A0[4], A1[4], B0[2][2][2], B1[2][2][2];
  loadA(A0, 0);
  loadB(B0, 0);
  int d = 0;
  for (int k0 = 0; k0 < K; k0 += 64) {
    kstep(A0, B0, A1, B1, k0, d); d ^= 1;
    if (k0 + 32 < K) { kstep(A1, B1, A0, B0, k0 + 32, d); d ^= 1; }
  }

  // epilogue: C/D layout col=lane&31, row=(g&3)+8*(g>>2)+4*(lane>>5)
  #pragma unroll
  for (int nf = 0; nf < 2; nf++) {
    const int col = n0 + nf * 32 + lr;
    const float* bp = bias;
    float* Cp = C0;
    int cc = col;
    if (QKV) {
      const int sel = col >> 8;
      cc = col & 255;
      Cp = sel == 0 ? C0 : (sel == 1 ? C1 : C2);
      bp = sel == 0 ? bias : (sel == 1 ? bias1 : bias2);
    }
    const float bb = (col < Nreal) ? bp[cc] : 0.f;
    #pragma unroll
    for (int g = 0; g < 16; g++) {
      const long row = m0 + wm * 32 + (g & 3) + 8 * (g >> 2) + 4 * lg;
      float v = acc[nf][g] + bb;
      if (ACT) v = fmaxf(v, 0.f);
      if (col < Nreal) {
        if (WF32) Cp[row * (long)ldc + cc] = v;
        if (WF16) {
          const f16 hi = (f16)v;
          Chi[row * (long)ldf + col] = hi;
          Clo[row * (long)ldf + col] = (f16)(v - (float)hi);
        }
      }
    }
  }
}

// ---------------------------------------------------------------------------
// Weight transpose + f16 hi/lo split into packed frag layout
// dst[(n>>5)*(K/8) + (k>>3)][hl][n&31][k&7]. blockIdx.y selects target.
// ---------------------------------------------------------------------------
__global__ __launch_bounds__(256) void wsplit_k(
    const float* __restrict__ W_in, const float* __restrict__ Wq,
    const float* __restrict__ Wk, const float* __restrict__ Wv,
    const float* __restrict__ Wo, const float* __restrict__ Wf1,
    const float* __restrict__ Wf2, const float* __restrict__ Ws1,
    const float* __restrict__ Wout,
    f16* __restrict__ WinP, f16* __restrict__ WqkvP, f16* __restrict__ WoP,
    f16* __restrict__ Wf1P, f16* __restrict__ Wf2P, f16* __restrict__ Ws1P,
    f16* __restrict__ WoutP)
{
  const int y = blockIdx.y;
  const long idx = (long)blockIdx.x * 256 + threadIdx.x;
  int Npad, Kpad, Ksrc;
  f16* dst;
  switch (y) {
    case 0: Npad = 256; Kpad = 288; Ksrc = 257; dst = WinP;  break;
    case 1: Npad = 768; Kpad = 256; Ksrc = 256; dst = WqkvP; break;
    case 2: Npad = 256; Kpad = 256; Ksrc = 256; dst = WoP;   break;
    case 3: Npad = 512; Kpad = 256; Ksrc = 256; dst = Wf1P;  break;
    case 4: Npad = 256; Kpad = 512; Ksrc = 512; dst = Wf2P;  break;
    case 5: Npad = 128; Kpad = 256; Ksrc = 256; dst = Ws1P;  break;
    default: Npad = 384; Kpad = 256; Ksrc = 256; dst = WoutP; break;
  }
  if (idx >= (long)Npad * Kpad) return;
  const int n = (int)(idx / Kpad), k = (int)(idx % Kpad);
  float v = 0.f;
  if (k < Ksrc) {
    switch (y) {
      case 0: v = W_in[(long)k * 256 + n]; break;
      case 1: { const int sel = n >> 8;
                const float* s = sel == 0 ? Wq : (sel == 1 ? Wk : Wv);
                v = s[(long)k * 256 + (n & 255)]; } break;
      case 2: v = Wo[(long)k * 256 + n]; break;
      case 3: v = Wf1[(long)k * 512 + n]; break;
      case 4: v = Wf2[(long)k * 256 + n]; break;
      case 5: v = Ws1[(long)k * 128 + n]; break;
      default: v = (n < 257) ? Wout[(long)k * 257 + n] : 0.f; break;
    }
  }
  const long base = ((long)(n >> 5) * (Kpad >> 3) + (k >> 3)) * 512 + (n & 31) * 8 + (k & 7);
  const f16 hi = (f16)v;
  dst[base] = hi;            // hl = 0
  dst[base + 256] = (f16)(v - (float)hi);   // hl = 1
}

// ---------------------------------------------------------------------------
// Per-time-frame attention over channels; writes ctx as f16 hi/lo.
// ---------------------------------------------------------------------------
template<int NCc>
__global__ __launch_bounds__(256) void attn_k(
    const float* __restrict__ Q, const float* __restrict__ Ksp,
    const float* __restrict__ Vsp, f16* __restrict__ chi,
    f16* __restrict__ clo, const int* __restrict__ alive)
{
  if (alive && *alive == 0) return;
  const int w = threadIdx.x >> 6;   // head
  const int l = threadIdx.x & 63;   // dh lane
  for (int rr = 0; rr < 4; rr++) {
    const long r = (long)blockIdx.x * 4 + rr;
    const float qv = Q[r * HD + w * DHD + l];
    float sc[NCc];
    #pragma unroll
    for (int c = 0; c < NCc; c++) {
      float p = qv * Ksp[((long)c * RR + r) * HD + w * DHD + l];
      #pragma unroll
      for (int s = 32; s > 0; s >>= 1) p += __shfl_xor(p, s, 64);
      sc[c] = p * 0.125f;   // 1/sqrt(64)
    }
    float m = sc[0];
    #pragma unroll
    for (int c = 1; c < NCc; c++) m = fmaxf(m, sc[c]);
    float a[NCc];
    float den = 0.f;
    #pragma unroll
    for (int c = 0; c < NCc; c++) { a[c] = expf(sc[c] - m); den += a[c]; }
    float cv = 0.f;
    #pragma unroll
    for (int c = 0; c < NCc; c++)
      cv = fmaf(a[c] / den, Vsp[((long)c * RR + r) * HD + w * DHD + l], cv);
    const f16 hi = (f16)cv;
    chi[r * HD + w * DHD + l] = hi;
    clo[r * HD + w * DHD + l] = (f16)(cv - (float)hi);
  }
}

// ---------------------------------------------------------------------------
// O = LayerNorm(X + Y) * g + b over H=256. X from fp32 or hi/lo pair.
// ---------------------------------------------------------------------------
template<int XHL>
__global__ __launch_bounds__(256) void ln_res_k(
    const float* __restrict__ Xf, const f16* __restrict__ Xhi,
    const f16* __restrict__ Xlo, const float* __restrict__ Y,
    const float* __restrict__ g, const float* __restrict__ b,
    float* __restrict__ O, f16* __restrict__ Ohi, f16* __restrict__ Olo,
    const int* __restrict__ alive)
{
  if (alive && *alive == 0) return;
  __shared__ float red[2][8];
  const int tid = threadIdx.x;
  const int w = tid >> 6;
  for (int rr = 0; rr < 8; rr++) {
    const int p = rr & 1;
    const long r = (long)blockIdx.x * 8 + rr;
    float xv;
    if (XHL) xv = (float)Xhi[r * HD + tid] + (float)Xlo[r * HD + tid];
    else     xv = Xf[r * HD + tid];
    const float v = xv + Y[r * HD + tid];
    float s = v, sq = v * v;
    #pragma unroll
    for (int i = 32; i > 0; i >>= 1) {
      s += __shfl_xor(s, i, 64);
      sq += __shfl_xor(sq, i, 64);
    }
    if ((tid & 63) == 0) { red[p][w] = s; red[p][4 + w] = sq; }
    __syncthreads();
    const float mean = (red[p][0] + red[p][1] + red[p][2] + red[p][3]) * (1.f / HD);
    const float ex2 = (red[p][4] + red[p][5] + red[p][6] + red[p][7]) * (1.f / HD);
    const float var = ex2 - mean * mean;
    const float inv = 1.f / sqrtf(var + 1e-5f);
    const float o = (v - mean) * inv * g[tid] + b[tid];
    O[r * HD + tid] = o;
    const f16 hi = (f16)o;
    Ohi[r * HD + tid] = hi;
    Olo[r * HD + tid] = (f16)(o - (float)hi);
  }
}

// ---------------------------------------------------------------------------
// ACT ponder update (exact reference formulas). FIRST: state known
// (cum=0, rem=1, still=1, pc=0) and out is WRITTEN (no init pass needed).
// ---------------------------------------------------------------------------
template<int FIRST>
__global__ __launch_bounds__(256) void act_k(
    const float* __restrict__ s1, const float* __restrict__ Ws2,
    const float* __restrict__ bs2, const float* __restrict__ psa,
    const float* __restrict__ psb, const float* __restrict__ hh,
    float* __restrict__ cum, float* __restrict__ rem,
    float* __restrict__ still, float* __restrict__ pc,
    float* __restrict__ out, f16* __restrict__ outhi, f16* __restrict__ outlo,
    int lastIter, const int* __restrict__ alive, int* __restrict__ myFlag)
{
  if (!FIRST && alive && *alive == 0) return;
  __shared__ float red[2][4];
  const int tid = threadIdx.x;
  const int w = tid >> 6;
  for (int rr = 0; rr < 8; rr++) {
    const int p = rr & 1;
    const long r = (long)blockIdx.x * 8 + rr;
    float curv;
    if (!lastIter) {
      float pv = (tid < HF) ? s1[r * HF + tid] * Ws2[tid] : 0.f;
      #pragma unroll
      for (int i = 32; i > 0; i >>= 1) pv += __shfl_xor(pv, i, 64);
      if ((tid & 63) == 0) red[p][w] = pv;
      __syncthreads();
      const float s = red[p][0] + red[p][1] + red[p][2] + red[p][3] + bs2[0];
      const float z = (s - psa[0]) / (psb[0] + 1e-8f);
      curv = 1.f / (1.f + expf(-z));
    } else {
      curv = 1.f;
    }
    const float cu = FIRST ? 0.f : cum[r];
    const float re = FIRST ? 1.f : rem[r];
    const float st = FIRST ? 1.f : still[r];
    const float pp = FIRST ? 0.f : pc[r];
    const float cum_n = cu + curv * st;
    float pc_n = pp + st;
    const float still_n = (cum_n < 0.9999f) ? 1.f : 0.f;
    const float wgt = curv * still_n + re * (1.f - still_n);
    const float prev = FIRST ? 0.f : out[r * HD + tid];
    const float newv = prev + hh[r * HD + tid] * wgt;
    out[r * HD + tid] = newv;
    const f16 hi = (f16)newv;
    outhi[r * HD + tid] = hi;
    outlo[r * HD + tid] = (f16)(newv - (float)hi);
    const float rem_n = re - curv * still_n;
    pc_n += rem_n * (1.f - still_n);
    if (tid == 0) {
      cum[r] = cum_n; rem[r] = rem_n; still[r] = still_n; pc[r] = pc_n;
      if (still_n > 0.5f) *myFlag = 1;
    }
  }
}

__global__ void init_k(int* flags) {
  if (threadIdx.x < 8) flags[threadIdx.x] = 0;
}

__global__ __launch_bounds__(256) void pc_copy_k(const float* pc, float* o) {
  const int i = blockIdx.x * 256 + threadIdx.x;
  o[i] = pc[i];
}

// ---------------------------------------------------------------------------
extern "C" void kernel_launch(void* const* d_in, const int* in_sizes, int n_in,
                              void* d_out, int out_size, void* d_ws, size_t ws_size,
                              hipStream_t stream) {
  const float* x    = (const float*)d_in[0];
  const float* W_in = (const float*)d_in[1];
  const float* b_in = (const float*)d_in[2];
  const float* W_out= (const float*)d_in[3];
  const float* b_out= (const float*)d_in[4];
  const float* Wq   = (const float*)d_in[5];
  const float* bq   = (const float*)d_in[6];
  const float* Wk   = (const float*)d_in[7];
  const float* bk   = (const float*)d_in[8];
  const float* Wv   = (const float*)d_in[9];
  const float* bv   = (const float*)d_in[10];
  const float* Wo   = (const float*)d_in[11];
  const float* bo   = (const float*)d_in[12];
  const float* ln1g = (const float*)d_in[13];
  const float* ln1b = (const float*)d_in[14];
  const float* Wf1  = (const float*)d_in[15];
  const float* bf1  = (const float*)d_in[16];
  const float* Wf2  = (const float*)d_in[17];
  const float* bf2  = (const float*)d_in[18];
  const float* ln2g = (const float*)d_in[19];
  const float* ln2b = (const float*)d_in[20];
  const float* Ws1  = (const float*)d_in[21];
  const float* bs1  = (const float*)d_in[22];
  const float* Ws2  = (const float*)d_in[23];
  const float* bs2  = (const float*)d_in[24];
  const float* psa  = (const float*)d_in[25];
  const float* psb  = (const float*)d_in[26];

  float* ws = (float*)d_ws;
  long off = 0;
  auto alloc = [&](long n) { float* p = ws + off; off += n; return p; };
  float* Ks   = alloc((long)CH * RR * HD);
  float* Vs   = alloc((long)CH * RR * HD);
  float* Qb   = alloc((long)RR * HD);
  float* gb   = alloc((long)RR * HD);
  float* h1   = alloc((long)RR * HD);
  float* hh   = alloc((long)RR * HD);
  float* outb = alloc((long)RR * HD);
  f16* lin1hi = (f16*)alloc((long)RR * HD / 2);
  f16* lin1lo = (f16*)alloc((long)RR * HD / 2);
  f16* ctxhi  = (f16*)alloc((long)RR * HD / 2);
  f16* ctxlo  = (f16*)alloc((long)RR * HD / 2);
  f16* h1hi   = (f16*)alloc((long)RR * HD / 2);
  f16* h1lo   = (f16*)alloc((long)RR * HD / 2);
  f16* hhhi   = (f16*)alloc((long)RR * HD / 2);
  f16* hhlo   = (f16*)alloc((long)RR * HD / 2);
  f16* t1hi   = (f16*)alloc((long)RR * WN / 2);
  f16* t1lo   = (f16*)alloc((long)RR * WN / 2);
  f16* outhi  = (f16*)alloc((long)RR * HD / 2);
  f16* outlo  = (f16*)alloc((long)RR * HD / 2);
  f16* WinP   = (f16*)alloc(2 * 256 * 288 / 2);
  f16* WqkvP  = (f16*)alloc(2 * 768 * 256 / 2);
  f16* WoP    = (f16*)alloc(2 * 256 * 256 / 2);
  f16* Wf1P   = (f16*)alloc(2 * 512 * 256 / 2);
  f16* Wf2P   = (f16*)alloc(2 * 256 * 512 / 2);
  f16* Ws1P   = (f16*)alloc(2 * 128 * 256 / 2);
  f16* WoutP  = (f16*)alloc(2 * 384 * 256 / 2);
  float* cum  = alloc(RR);
  float* rem  = alloc(RR);
  float* still= alloc(RR);
  float* pc   = alloc(RR);
  int* flags  = (int*)alloc(8);
  float* s1   = Qb;   // alias: Qb consumed by attn before s1 written

  init_k<<<1, 256, 0, stream>>>(flags);
  wsplit_k<<<dim3(768, 7), 256, 0, stream>>>(
      W_in, Wq, Wk, Wv, Wo, Wf1, Wf2, Ws1, W_out,
      WinP, WqkvP, WoP, Wf1P, Wf2P, Ws1P, WoutP);

  for (int ci = 0; ci < CH; ci++) {
    const int* al = (ci == 0) ? nullptr : (flags + ci - 1);
    // lin1 = relu(x[:,ci] @ W_in + b_in) -> f16 hi/lo only
    gemm2<1, 0, 1, 0, 1><<<dim3(128, 4), 256, 0, stream>>>(
        nullptr, nullptr, KXP, x + (long)ci * TT * FB, (long)CH * TT * FB,
        WinP, b_in, b_in, b_in, nullptr, nullptr, nullptr, HD,
        lin1hi, lin1lo, HD, HD, al);
    // fused Q/K/V projections (N=768)
    gemm2<0, 1, 0, 1, 0><<<dim3(128, 12), 256, 0, stream>>>(
        lin1hi, lin1lo, HD, nullptr, 0, WqkvP, bq, bk, bv,
        Qb, Ks + (long)ci * RR * HD, Vs + (long)ci * RR * HD, HD,
        nullptr, nullptr, HD, 768, al);
    // attention over channels 0..ci
    switch (ci) {
      case 0: attn_k<1><<<4096, 256, 0, stream>>>(Qb, Ks, Vs, ctxhi, ctxlo, al); break;
      case 1: attn_k<2><<<4096, 256, 0, stream>>>(Qb, Ks, Vs, ctxhi, ctxlo, al); break;
      case 2: attn_k<3><<<4096, 256, 0, stream>>>(Qb, Ks, Vs, ctxhi, ctxlo, al); break;
      case 3: attn_k<4><<<4096, 256, 0, stream>>>(Qb, Ks, Vs, ctxhi, ctxlo, al); break;
      case 4: attn_k<5><<<4096, 256, 0, stream>>>(Qb, Ks, Vs, ctxhi, ctxlo, al); break;
      case 5: attn_k<6><<<4096, 256, 0, stream>>>(Qb, Ks, Vs, ctxhi, ctxlo, al); break;
      case 6: attn_k<7><<<4096, 256, 0, stream>>>(Qb, Ks, Vs, ctxhi, ctxlo, al); break;
      default: attn_k<8><<<4096, 256, 0, stream>>>(Qb, Ks, Vs, ctxhi, ctxlo, al); break;
    }
    // h1 = LN(lin1 + ctx @ Wo + bo)
    gemm2<0, 1, 0, 0, 0><<<dim3(128, 4), 256, 0, stream>>>(
        ctxhi, ctxlo, HD, nullptr, 0, WoP, bo, bo, bo,
        gb, nullptr, nullptr, HD, nullptr, nullptr, HD, HD, al);
    ln_res_k<1><<<2048, 256, 0, stream>>>(nullptr, lin1hi, lin1lo, gb,
                                          ln1g, ln1b, h1, h1hi, h1lo, al);
    // hh = LN(h1 + relu(h1@Wf1+bf1)@Wf2+bf2)
    gemm2<1, 0, 1, 0, 0><<<dim3(128, 8), 256, 0, stream>>>(
        h1hi, h1lo, HD, nullptr, 0, Wf1P, bf1, bf1, bf1,
        nullptr, nullptr, nullptr, WN, t1hi, t1lo, WN, WN, al);
    gemm2<0, 1, 0, 0, 0><<<dim3(128, 4), 256, 0, stream>>>(
        t1hi, t1lo, WN, nullptr, 0, Wf2P, bf2, bf2, bf2,
        gb, nullptr, nullptr, HD, nullptr, nullptr, HD, HD, al);
    ln_res_k<0><<<2048, 256, 0, stream>>>(h1, nullptr, nullptr, gb,
                                          ln2g, ln2b, hh, hhhi, hhlo, al);
    // ponder head + ACT state update
    if (ci < CH - 1)
      gemm2<1, 1, 0, 0, 0><<<dim3(128, 2), 256, 0, stream>>>(
          hhhi, hhlo, HD, nullptr, 0, Ws1P, bs1, bs1, bs1,
          s1, nullptr, nullptr, HF, nullptr, nullptr, HD, HF, al);
    if (ci == 0)
      act_k<1><<<2048, 256, 0, stream>>>(s1, Ws2, bs2, psa, psb, hh, cum, rem,
                                         still, pc, outb, outhi, outlo, 0,
                                         nullptr, flags + 0);
    else
      act_k<0><<<2048, 256, 0, stream>>>(s1, Ws2, bs2, psa, psb, hh, cum, rem,
                                         still, pc, outb, outhi, outlo,
                                         (ci == CH - 1) ? 1 : 0, al, flags + ci);
  }
  // encoder_out = relu(out @ W_out + b_out)
  gemm2<1, 1, 0, 0, 0><<<dim3(128, 6), 256, 0, stream>>>(
      outhi, outlo, HD, nullptr, 0, WoutP, b_out, b_out, b_out,
      (float*)d_out, nullptr, nullptr, FB, nullptr, nullptr, HD, FB, nullptr);
  pc_copy_k<<<64, 256, 0, stream>>>(pc, (float*)d_out + (long)RR * FB);
}